// Round 1
// baseline (12848.929 us; speedup 1.0000x reference)
//
#include <hip/hip_runtime.h>
#include <hip/hip_bf16.h>
#include <math.h>

#define B 512
#define S 256
#define D 128
#define H 256
#define G4 1024   // 4*H
#define NS 32     // n_stock tokens
#define NH 8      // heads
#define DH 32     // head dim

// ---------- helpers ----------
__device__ __forceinline__ float sigm(float v) { return 1.f / (1.f + __expf(-v)); }

template<typename T> __device__ __forceinline__ T toHS(float v);
template<> __device__ __forceinline__ float toHS<float>(float v) { return v; }
template<> __device__ __forceinline__ __hip_bfloat16 toHS<__hip_bfloat16>(float v) { return __float2bfloat16(v); }
__device__ __forceinline__ float fromHS(float v) { return v; }
__device__ __forceinline__ float fromHS(__hip_bfloat16 v) { return __bfloat162float(v); }

// ---------- prep: transposes + fused biases ----------
__global__ void prep_kernel(const float* __restrict__ s_wih, const float* __restrict__ s_whh,
                            const float* __restrict__ s_bih, const float* __restrict__ s_bhh,
                            const float* __restrict__ m_wih, const float* __restrict__ m_whh,
                            const float* __restrict__ m_bih, const float* __restrict__ m_bhh,
                            const float* __restrict__ stw, const float* __restrict__ mtw,
                            float* __restrict__ wihT_s, float* __restrict__ whhT_s,
                            float* __restrict__ wihT_m, float* __restrict__ whhT_m,
                            float* __restrict__ trWT_s, float* __restrict__ trWT_m,
                            float* __restrict__ bias4_s, float* __restrict__ bias4_m)
{
    int tid = blockIdx.x * blockDim.x + threadIdx.x;
    int stride = gridDim.x * blockDim.x;
    for (int i = tid; i < D * G4; i += stride) { int k = i / G4, g = i % G4; wihT_s[i] = s_wih[g * D + k]; wihT_m[i] = m_wih[g * D + k]; }
    for (int i = tid; i < H * G4; i += stride) { int k = i / G4, g = i % G4; whhT_s[i] = s_whh[g * H + k]; whhT_m[i] = m_whh[g * H + k]; }
    for (int i = tid; i < D * D; i += stride)  { int k = i / D,  d = i % D;  trWT_s[i] = stw[d * D + k];  trWT_m[i] = mtw[d * D + k]; }
    for (int i = tid; i < G4; i += stride)     { bias4_s[i] = s_bih[i] + s_bhh[i]; bias4_m[i] = m_bih[i] + m_bhh[i]; }
}

// ---------- LSTM: one WG per (lstm, 8-batch tile), persistent over 256 steps ----------
template<typename HT>
__global__ __launch_bounds__(512) void lstm_kernel(
    const float* __restrict__ x,
    const float* __restrict__ trWT_s, const float* __restrict__ trb_s,
    const float* __restrict__ trWT_m, const float* __restrict__ trb_m,
    const float* __restrict__ wihT_s, const float* __restrict__ whhT_s, const float* __restrict__ bias4_s,
    const float* __restrict__ wihT_m, const float* __restrict__ whhT_m, const float* __restrict__ bias4_m,
    HT* __restrict__ hs_s, HT* __restrict__ hs_m)
{
    const int L = blockIdx.y;
    const float* trWT  = L ? trWT_m  : trWT_s;
    const float* trb   = L ? trb_m   : trb_s;
    const float* wihT  = L ? wihT_m  : wihT_s;
    const float* whhT  = L ? whhT_m  : whhT_s;
    const float* bias4 = L ? bias4_m : bias4_s;
    HT* hs = L ? hs_m : hs_s;

    const int b0  = blockIdx.x * 8;
    const int tid = threadIdx.x;          // 512 threads

    __shared__ float xbuf[8][D];          // raw x rows         4 KB
    __shared__ float xtr[D][8];           // transformed x [k][b] 4 KB
    __shared__ float hbuf[H][8];          // h state [k][b]     8 KB
    __shared__ float gbuf[G4][8];         // gates [g][b]      32 KB

    float c[8];
#pragma unroll
    for (int b = 0; b < 8; b++) c[b] = 0.f;
    for (int i = tid; i < H * 8; i += 512) (&hbuf[0][0])[i] = 0.f;
    __syncthreads();

    const float bv0 = bias4[tid];
    const float bv1 = bias4[tid + 512];
    const int d_tr = tid & 127;
    const int bp   = (tid >> 7) * 2;

    for (int t = 0; t < S; ++t) {
        // stage x rows for this timestep
        for (int i = tid; i < 8 * D; i += 512) {
            int b = i >> 7, d = i & 127;
            xbuf[b][d] = x[((size_t)(b0 + b) * S + t) * D + d];
        }
        __syncthreads();                                   // A: xbuf ready, prev hbuf visible
        // fused input transform: tanh(x @ trW^T + trb)
        {
            float a0 = trb[d_tr], a1 = a0;
#pragma unroll 4
            for (int k = 0; k < D; ++k) {
                float w = trWT[k * D + d_tr];
                a0 = fmaf(xbuf[bp][k],     w, a0);
                a1 = fmaf(xbuf[bp + 1][k], w, a1);
            }
            xtr[d_tr][bp]     = tanhf(a0);
            xtr[d_tr][bp + 1] = tanhf(a1);
        }
        __syncthreads();                                   // C: xtr ready
        // gates: thread owns columns {tid, tid+512}
        {
            float acc0[8], acc1[8];
#pragma unroll
            for (int b = 0; b < 8; b++) { acc0[b] = bv0; acc1[b] = bv1; }
#pragma unroll 2
            for (int k = 0; k < D; ++k) {
                float w0 = wihT[k * G4 + tid];
                float w1 = wihT[k * G4 + tid + 512];
                float xv[8];
                *(float4*)&xv[0] = *(const float4*)&xtr[k][0];
                *(float4*)&xv[4] = *(const float4*)&xtr[k][4];
#pragma unroll
                for (int b = 0; b < 8; b++) { acc0[b] = fmaf(xv[b], w0, acc0[b]); acc1[b] = fmaf(xv[b], w1, acc1[b]); }
            }
#pragma unroll 2
            for (int k = 0; k < H; ++k) {
                float w0 = whhT[k * G4 + tid];
                float w1 = whhT[k * G4 + tid + 512];
                float hv[8];
                *(float4*)&hv[0] = *(const float4*)&hbuf[k][0];
                *(float4*)&hv[4] = *(const float4*)&hbuf[k][4];
#pragma unroll
                for (int b = 0; b < 8; b++) { acc0[b] = fmaf(hv[b], w0, acc0[b]); acc1[b] = fmaf(hv[b], w1, acc1[b]); }
            }
#pragma unroll
            for (int b = 0; b < 8; b++) { gbuf[tid][b] = acc0[b]; gbuf[tid + 512][b] = acc1[b]; }
        }
        __syncthreads();                                   // B: gbuf ready
        // state update: hidden unit j = tid (tid < 256); gate order i,f,g,o
        if (tid < H) {
            float hnew[8];
#pragma unroll
            for (int b = 0; b < 8; b++) {
                float ig = gbuf[tid][b];
                float fg = gbuf[H + tid][b];
                float gg = gbuf[2 * H + tid][b];
                float og = gbuf[3 * H + tid][b];
                float cc = sigm(fg) * c[b] + sigm(ig) * tanhf(gg);
                c[b] = cc;
                hnew[b] = sigm(og) * tanhf(cc);
            }
#pragma unroll
            for (int b = 0; b < 8; b++) {
                hbuf[tid][b] = hnew[b];
                hs[((size_t)(b0 + b) * S + t) * H + tid] = toHS<HT>(hnew[b]);
            }
        }
        // next-iter barrier A orders hbuf writes vs gate reads
    }
}

// ---------- attention context: score = hs . h_last, dist = score/sum, ctx = dist . hs ----------
template<typename HT>
__global__ __launch_bounds__(256) void attn_ctx_kernel(const HT* __restrict__ hs_s, const HT* __restrict__ hs_m,
                                                       float* __restrict__ ctx_s, float* __restrict__ ctx_m)
{
    const int b = blockIdx.x;
    const int L = blockIdx.y;
    const HT* hs = (L ? hs_m : hs_s) + (size_t)b * S * H;
    float* ctx = (L ? ctx_m : ctx_s) + b * H;
    const int tid = threadIdx.x;

    __shared__ float hlast[H];
    __shared__ float dist[S];
    __shared__ float red[4];

    hlast[tid] = fromHS(hs[(size_t)(S - 1) * H + tid]);
    __syncthreads();

    float s = 0.f;
    {
        const HT* row = hs + (size_t)tid * H;
#pragma unroll 4
        for (int h = 0; h < H; ++h) s = fmaf(fromHS(row[h]), hlast[h], s);
    }
    float v = s;
    for (int o = 32; o > 0; o >>= 1) v += __shfl_down(v, o);
    if ((tid & 63) == 0) red[tid >> 6] = v;
    __syncthreads();
    float denom = red[0] + red[1] + red[2] + red[3];
    dist[tid] = s / denom;
    __syncthreads();

    float acc = 0.f;
    for (int t = 0; t < S; ++t) acc = fmaf(dist[t], fromHS(hs[(size_t)t * H + tid]), acc);
    ctx[tid] = acc;
}

// ---------- tail: norm + MHA(32 tokens) + MLP + pool + final, one WG per batch ----------
__global__ __launch_bounds__(256) void tail_kernel(
    const float* __restrict__ ctx_s, const float* __restrict__ ctx_m,
    const float* __restrict__ norm_w, const float* __restrict__ norm_b,
    const float* __restrict__ macro_w,
    const float* __restrict__ in_w, const float* __restrict__ in_b,
    const float* __restrict__ outp_w, const float* __restrict__ outp_b,
    const float* __restrict__ w1, const float* __restrict__ b1,
    const float* __restrict__ w2, const float* __restrict__ b2,
    const float* __restrict__ fw, const float* __restrict__ fb,
    float* __restrict__ out)
{
    const int b = blockIdx.x;
    const int tid = threadIdx.x;   // 256

    __shared__ float ml[NS][H];    // becomes h1 after residual
    __shared__ float buf[NS][H];   // att concat; later mlp hidden chunk
    __shared__ float qh[NS][DH], kh[NS][DH], vh[NS][DH], sc[NS][NS];
    __shared__ float red[4];

    // --- mean/std (ddof=1) over H of ctx_s[b], then ml = nw*z + nb + mw*ctx_m ---
    float cs = ctx_s[b * H + tid];
    float v = cs;
    for (int o = 32; o > 0; o >>= 1) v += __shfl_down(v, o);
    if ((tid & 63) == 0) red[tid >> 6] = v;
    __syncthreads();
    float mean = (red[0] + red[1] + red[2] + red[3]) * (1.f / H);
    float dv = cs - mean;
    __syncthreads();
    v = dv * dv;
    for (int o = 32; o > 0; o >>= 1) v += __shfl_down(v, o);
    if ((tid & 63) == 0) red[tid >> 6] = v;
    __syncthreads();
    float stdv = sqrtf((red[0] + red[1] + red[2] + red[3]) * (1.f / (H - 1))) + 1e-8f;
    float z = dv / stdv;
    float cm = ctx_m[b * H + tid];
    float mwv = macro_w[0];
    for (int n = 0; n < NS; ++n)
        ml[n][tid] = norm_w[n * H + tid] * z + norm_b[n * H + tid] + mwv * cm;
    __syncthreads();

    // --- MHA per head ---
    const int dloc = tid & 31;
    const int iset = tid >> 5;
    const float scale = 0.17677669529663687f;   // 1/sqrt(32)
    for (int h = 0; h < NH; ++h) {
        {   // q,k,v projections for this head
            int rq = h * DH + dloc;
            int rk = H + h * DH + dloc;
            int rv = 2 * H + h * DH + dloc;
            float aq[4], ak[4], av[4];
#pragma unroll
            for (int r = 0; r < 4; r++) { aq[r] = in_b[rq]; ak[r] = in_b[rk]; av[r] = in_b[rv]; }
            for (int k = 0; k < H; ++k) {
                float wq = in_w[rq * H + k];
                float wk = in_w[rk * H + k];
                float wv = in_w[rv * H + k];
#pragma unroll
                for (int r = 0; r < 4; r++) {
                    float m = ml[iset + 8 * r][k];
                    aq[r] = fmaf(m, wq, aq[r]); ak[r] = fmaf(m, wk, ak[r]); av[r] = fmaf(m, wv, av[r]);
                }
            }
#pragma unroll
            for (int r = 0; r < 4; r++) { qh[iset + 8 * r][dloc] = aq[r]; kh[iset + 8 * r][dloc] = ak[r]; vh[iset + 8 * r][dloc] = av[r]; }
        }
        __syncthreads();
        {   // scores
            int i = tid >> 3;
            int j0 = (tid & 7) * 4;
            float a[4] = {0.f, 0.f, 0.f, 0.f};
            for (int d = 0; d < DH; ++d) {
                float q = qh[i][d];
#pragma unroll
                for (int jj = 0; jj < 4; jj++) a[jj] = fmaf(q, kh[j0 + jj][d], a[jj]);
            }
#pragma unroll
            for (int jj = 0; jj < 4; jj++) sc[i][j0 + jj] = a[jj] * scale;
        }
        __syncthreads();
        if (tid < NS) {   // softmax row
            float mx = -1e30f;
            for (int j = 0; j < NS; j++) mx = fmaxf(mx, sc[tid][j]);
            float sm = 0.f, e[NS];
            for (int j = 0; j < NS; j++) { e[j] = __expf(sc[tid][j] - mx); sm += e[j]; }
            float inv = 1.f / sm;
            for (int j = 0; j < NS; j++) sc[tid][j] = e[j] * inv;
        }
        __syncthreads();
        {   // attn = attw @ v
            int i = tid >> 3;
            int d0 = (tid & 7) * 4;
            float a[4] = {0.f, 0.f, 0.f, 0.f};
            for (int j = 0; j < NS; ++j) {
                float sv = sc[i][j];
#pragma unroll
                for (int dd = 0; dd < 4; dd++) a[dd] = fmaf(sv, vh[j][d0 + dd], a[dd]);
            }
#pragma unroll
            for (int dd = 0; dd < 4; dd++) buf[i][h * DH + d0 + dd] = a[dd];
        }
        __syncthreads();
    }

    // --- out_proj + residual: h1 = ml + att @ outp_w^T + outp_b ---
    {
        float acc32[NS];
        float ob = outp_b[tid];
#pragma unroll
        for (int t = 0; t < NS; t++) acc32[t] = ob;
        for (int k = 0; k < H; ++k) {
            float w = outp_w[tid * H + k];
#pragma unroll
            for (int t = 0; t < NS; t++) acc32[t] = fmaf(buf[t][k], w, acc32[t]);
        }
#pragma unroll
        for (int t = 0; t < NS; t++) ml[t][tid] += acc32[t];
    }
    __syncthreads();

    // --- MLP: 4 chunks of 256 hidden units ---
    float acc_o[NS];
    {
        float b2v = b2[tid];
#pragma unroll
        for (int t = 0; t < NS; t++) acc_o[t] = b2v;
    }
    for (int jc = 0; jc < 4; ++jc) {
        float hid[NS];
        {
            float b1v = b1[jc * H + tid];
#pragma unroll
            for (int t = 0; t < NS; t++) hid[t] = b1v;
            for (int k = 0; k < H; ++k) {
                float w = w1[(size_t)(jc * H + tid) * H + k];
#pragma unroll
                for (int t = 0; t < NS; t++) hid[t] = fmaf(ml[t][k], w, hid[t]);
            }
        }
        __syncthreads();   // previous buf readers done
#pragma unroll
        for (int t = 0; t < NS; t++) buf[t][tid] = fmaxf(hid[t], 0.f);
        __syncthreads();
        for (int k = 0; k < H; ++k) {
            float w = w2[(size_t)tid * G4 + jc * H + k];
#pragma unroll
            for (int t = 0; t < NS; t++) acc_o[t] = fmaf(buf[t][k], w, acc_o[t]);
        }
        __syncthreads();
    }

    // --- out = tanh(h1 + mlp_out), pool over tokens, final dot ---
    float p = 0.f;
#pragma unroll
    for (int t = 0; t < NS; t++) p += tanhf(ml[t][tid] + acc_o[t]);
    p *= (1.f / NS);
    v = p * fw[tid];
    for (int o = 32; o > 0; o >>= 1) v += __shfl_down(v, o);
    if ((tid & 63) == 0) red[tid >> 6] = v;
    __syncthreads();
    if (tid == 0) out[b] = red[0] + red[1] + red[2] + red[3] + fb[0];
}

// ---------- host ----------
extern "C" void kernel_launch(void* const* d_in, const int* in_sizes, int n_in,
                              void* d_out, int out_size, void* d_ws, size_t ws_size,
                              hipStream_t stream) {
    const float* x      = (const float*)d_in[0];
    const float* stw    = (const float*)d_in[1];
    const float* stb    = (const float*)d_in[2];
    const float* mtw    = (const float*)d_in[3];
    const float* mtb    = (const float*)d_in[4];
    const float* s_wih  = (const float*)d_in[5];
    const float* s_whh  = (const float*)d_in[6];
    const float* s_bih  = (const float*)d_in[7];
    const float* s_bhh  = (const float*)d_in[8];
    const float* m_wih  = (const float*)d_in[9];
    const float* m_whh  = (const float*)d_in[10];
    const float* m_bih  = (const float*)d_in[11];
    const float* m_bhh  = (const float*)d_in[12];
    const float* norm_w = (const float*)d_in[13];
    const float* norm_b = (const float*)d_in[14];
    const float* macro_w= (const float*)d_in[15];
    const float* in_w   = (const float*)d_in[16];
    const float* in_b   = (const float*)d_in[17];
    const float* outp_w = (const float*)d_in[18];
    const float* outp_b = (const float*)d_in[19];
    const float* w1     = (const float*)d_in[20];
    const float* b1     = (const float*)d_in[21];
    const float* w2     = (const float*)d_in[22];
    const float* b2     = (const float*)d_in[23];
    const float* fw     = (const float*)d_in[24];
    const float* fb     = (const float*)d_in[25];
    float* out = (float*)d_out;

    // workspace layout
    float* wsf     = (float*)d_ws;
    float* wihT_s  = wsf;                    // 128*1024
    float* whhT_s  = wihT_s + D * G4;        // 256*1024
    float* wihT_m  = whhT_s + H * G4;
    float* whhT_m  = wihT_m + D * G4;
    float* trWT_s  = whhT_m + H * G4;        // 128*128
    float* trWT_m  = trWT_s + D * D;
    float* bias4_s = trWT_m + D * D;         // 1024
    float* bias4_m = bias4_s + G4;
    float* ctx_s   = bias4_m + G4;           // 512*256
    float* ctx_m   = ctx_s + B * H;
    char*  hsbase  = (char*)(ctx_m + B * H);

    size_t small_bytes = (size_t)((char*)hsbase - (char*)d_ws);
    const size_t hs_elems = (size_t)B * S * H;                 // 33,554,432 per LSTM
    bool f32hs = ws_size >= small_bytes + 2 * hs_elems * sizeof(float);

    prep_kernel<<<64, 256, 0, stream>>>(s_wih, s_whh, s_bih, s_bhh,
                                        m_wih, m_whh, m_bih, m_bhh,
                                        stw, mtw,
                                        wihT_s, whhT_s, wihT_m, whhT_m,
                                        trWT_s, trWT_m, bias4_s, bias4_m);

    if (f32hs) {
        float* hs_s = (float*)hsbase;
        float* hs_m = hs_s + hs_elems;
        lstm_kernel<float><<<dim3(B / 8, 2), 512, 0, stream>>>(
            x, trWT_s, stb, trWT_m, mtb,
            wihT_s, whhT_s, bias4_s, wihT_m, whhT_m, bias4_m, hs_s, hs_m);
        attn_ctx_kernel<float><<<dim3(B, 2), 256, 0, stream>>>(hs_s, hs_m, ctx_s, ctx_m);
    } else {
        __hip_bfloat16* hs_s = (__hip_bfloat16*)hsbase;
        __hip_bfloat16* hs_m = hs_s + hs_elems;
        lstm_kernel<__hip_bfloat16><<<dim3(B / 8, 2), 512, 0, stream>>>(
            x, trWT_s, stb, trWT_m, mtb,
            wihT_s, whhT_s, bias4_s, wihT_m, whhT_m, bias4_m, hs_s, hs_m);
        attn_ctx_kernel<__hip_bfloat16><<<dim3(B, 2), 256, 0, stream>>>(hs_s, hs_m, ctx_s, ctx_m);
    }

    tail_kernel<<<B, 256, 0, stream>>>(ctx_s, ctx_m,
                                       norm_w, norm_b, macro_w,
                                       in_w, in_b, outp_w, outp_b,
                                       w1, b1, w2, b2, fw, fb, out);
}

// Round 4
// 5395.370 us; speedup vs baseline: 2.3815x; 2.3815x over previous
//
#include <hip/hip_runtime.h>
#include <hip/hip_bf16.h>
#include <math.h>

#define B 512
#define S 256
#define D 128
#define H 256
#define G4 1024
#define NS 32
#define NH 8
#define DH 32

typedef _Float16 half8 __attribute__((ext_vector_type(8)));
typedef _Float16 half4v __attribute__((ext_vector_type(4)));
typedef float f32x4 __attribute__((ext_vector_type(4)));

__device__ __forceinline__ float sigm(float v) { return 1.f / (1.f + __expf(-v)); }
__device__ __forceinline__ float tanh_fast(float x) { float e = __expf(2.f * x); return 1.f - 2.f / (e + 1.f); }
__device__ __forceinline__ float cvtf(float v) { return v; }
__device__ __forceinline__ float cvtf(_Float16 v) { return (float)v; }

// ---------------- prep: fp16 weight slices in MFMA-friendly [n][k] layout ----------------
__global__ void prep_kernel(const float* __restrict__ s_wih, const float* __restrict__ s_whh,
                            const float* __restrict__ s_bih, const float* __restrict__ s_bhh,
                            const float* __restrict__ m_wih, const float* __restrict__ m_whh,
                            const float* __restrict__ m_bih, const float* __restrict__ m_bhh,
                            const float* __restrict__ stw, const float* __restrict__ mtw,
                            _Float16* __restrict__ W16h, _Float16* __restrict__ W16l,
                            float* __restrict__ biasP, _Float16* __restrict__ trW16)
{
    int tid = blockIdx.x * blockDim.x + threadIdx.x;
    int stride = gridDim.x * blockDim.x;
    for (int i = tid; i < 2 * 8 * 128 * 384; i += stride) {
        int k = i % 384; int n = (i / 384) % 128; int c = (i / (384 * 128)) % 8; int L = i / (384 * 128 * 8);
        int row = (n >> 5) * 256 + c * 32 + (n & 31);
        const float* wih = L ? m_wih : s_wih;
        const float* whh = L ? m_whh : s_whh;
        float v = (k < 128) ? wih[row * 128 + k] : whh[row * 256 + (k - 128)];
        W16h[i] = (_Float16)v;
    }
    for (int i = tid; i < 2 * 8 * 128 * 256; i += stride) {
        int k = i % 256; int n = (i / 256) % 128; int c = (i / (256 * 128)) % 8; int L = i / (256 * 128 * 8);
        int row = (n >> 5) * 256 + c * 32 + (n & 31);
        const float* whh = L ? m_whh : s_whh;
        float v = whh[row * 256 + k];
        _Float16 hi = (_Float16)v;
        W16l[i] = (_Float16)(v - (float)hi);
    }
    for (int i = tid; i < 2 * 8 * 128; i += stride) {
        int n = i % 128; int c = (i / 128) % 8; int L = i / (128 * 8);
        int row = (n >> 5) * 256 + c * 32 + (n & 31);
        biasP[i] = L ? (m_bih[row] + m_bhh[row]) : (s_bih[row] + s_bhh[row]);
    }
    for (int i = tid; i < 256 * 128; i += stride) {
        int k = i % 128, n = i / 128;
        trW16[i] = (_Float16)(n < 128 ? stw[n * 128 + k] : mtw[(n - 128) * 128 + k]);
    }
}

// ---------------- xtr: xtr16[L][b][t][d] = fp16(tanh(x @ trW^T + trb)), MFMA ----------------
__global__ __launch_bounds__(256, 1) void xtr_kernel(const float* __restrict__ x,
        const _Float16* __restrict__ trW16,
        const float* __restrict__ stb, const float* __restrict__ mtb,
        _Float16* __restrict__ xtr16)
{
    const int b = blockIdx.x;
    const int tid = threadIdx.x;
    const int w = tid >> 6, l = tid & 63, l15 = l & 15, l4 = l >> 4;

    __shared__ _Float16 xa[128 * 128];

    half8 bw[4][4];
#pragma unroll
    for (int kk = 0; kk < 4; kk++)
#pragma unroll
        for (int ni = 0; ni < 4; ni++)
            bw[kk][ni] = *(const half8*)(trW16 + (w * 64 + ni * 16 + l15) * 128 + kk * 32 + l4 * 8);
    float tb[4];
#pragma unroll
    for (int ni = 0; ni < 4; ni++) { int d = w * 64 + ni * 16 + l15; tb[ni] = d < 128 ? stb[d] : mtb[d - 128]; }

    for (int h2 = 0; h2 < 2; ++h2) {
        {
            int trow = tid >> 1, seg = tid & 1;
            const float* src = x + ((size_t)b * S + h2 * 128 + trow) * 128 + seg * 64;
            int swz = (trow & 7) << 4;
#pragma unroll
            for (int q8 = 0; q8 < 8; q8++) {
                float4 f0 = *(const float4*)(src + q8 * 8);
                float4 f1 = *(const float4*)(src + q8 * 8 + 4);
                half8 hv = { (_Float16)f0.x, (_Float16)f0.y, (_Float16)f0.z, (_Float16)f0.w,
                             (_Float16)f1.x, (_Float16)f1.y, (_Float16)f1.z, (_Float16)f1.w };
                int byte = ((seg * 64 + q8 * 8) * 2) ^ swz;
                *(half8*)((char*)(xa + trow * 128) + byte) = hv;
            }
        }
        __syncthreads();
        for (int mt = 0; mt < 8; ++mt) {
            int row = mt * 16 + l15;
            int swz = (row & 7) << 4;
            half8 af[4];
#pragma unroll
            for (int kk = 0; kk < 4; kk++) {
                int byte = ((kk * 32 + l4 * 8) * 2) ^ swz;
                af[kk] = *(const half8*)((const char*)(xa + row * 128) + byte);
            }
            f32x4 acc[4];
#pragma unroll
            for (int ni = 0; ni < 4; ni++) acc[ni] = (f32x4){ tb[ni], tb[ni], tb[ni], tb[ni] };
#pragma unroll
            for (int kk = 0; kk < 4; kk++)
#pragma unroll
                for (int ni = 0; ni < 4; ni++)
                    acc[ni] = __builtin_amdgcn_mfma_f32_16x16x32_f16(af[kk], bw[kk][ni], acc[ni], 0, 0, 0);
#pragma unroll
            for (int ni = 0; ni < 4; ni++) {
                int d = w * 64 + ni * 16 + l15;
                int Ls = d >> 7, dl = d & 127;
#pragma unroll
                for (int r = 0; r < 4; r++) {
                    int t = h2 * 128 + mt * 16 + l4 * 4 + r;
                    xtr16[(((size_t)Ls * B + b) * S + t) * 128 + dl] = (_Float16)tanh_fast(acc[ni][r]);
                }
            }
        }
        __syncthreads();
    }
}

// ---------------- persistent MFMA LSTM ----------------
template<typename HT>
__global__ __launch_bounds__(256, 1) void lstm_mfma(
    const _Float16* __restrict__ W16h, const _Float16* __restrict__ W16l,
    const float* __restrict__ biasP,
    const _Float16* __restrict__ xtr16,
    HT* __restrict__ hs, _Float16* __restrict__ hG, unsigned int* __restrict__ cnt)
{
    const int bid = blockIdx.x;
    const int sC = bid >> 5;
    const int g = bid & 31;
    const int L = g >> 4;
    const int bt = g & 15;
    const int b0 = bt * 32;
    const int tid = threadIdx.x;
    const int w = tid >> 6, l = tid & 63, l15 = l & 15, l4 = l >> 4;

    __shared__ _Float16 Ah[32 * 384];
    __shared__ _Float16 Al[32 * 256];
    __shared__ float gl[32][132];

    for (int i = tid; i < 32 * 384 * 2 / 16; i += 256) ((int4*)Ah)[i] = make_int4(0, 0, 0, 0);
    for (int i = tid; i < 32 * 256 * 2 / 16; i += 256) ((int4*)Al)[i] = make_int4(0, 0, 0, 0);

    const size_t wbh = ((size_t)(L * 8 + sC) * 128) * 384;
    const size_t wbl = ((size_t)(L * 8 + sC) * 128) * 256;
    half8 bwh[12][2], bwlo[8][2];
#pragma unroll
    for (int kk = 0; kk < 12; kk++)
#pragma unroll
        for (int ni = 0; ni < 2; ni++)
            bwh[kk][ni] = *(const half8*)(W16h + wbh + (size_t)(w * 32 + ni * 16 + l15) * 384 + kk * 32 + l4 * 8);
#pragma unroll
    for (int kk = 0; kk < 8; kk++)
#pragma unroll
        for (int ni = 0; ni < 2; ni++)
            bwlo[kk][ni] = *(const half8*)(W16l + wbl + (size_t)(w * 32 + ni * 16 + l15) * 256 + kk * 32 + l4 * 8);
    float bn[2];
#pragma unroll
    for (int ni = 0; ni < 2; ni++) bn[ni] = biasP[(L * 8 + sC) * 128 + w * 32 + ni * 16 + l15];

    const int b_pw = tid >> 3, jq = tid & 7;
    {
        const _Float16* src = xtr16 + (((size_t)L * B + b0 + b_pw) * S + 0) * 128 + jq * 16;
        half8 v0 = *(const half8*)src;
        half8 v1 = *(const half8*)(src + 8);
        int bswz = (b_pw & 7) << 4;
        *(half8*)((char*)(Ah + b_pw * 384) + ((jq * 32) ^ bswz)) = v0;
        *(half8*)((char*)(Ah + b_pw * 384) + ((jq * 32 + 16) ^ bswz)) = v1;
    }
    float cst[4] = { 0.f, 0.f, 0.f, 0.f };
    unsigned int* mycnt = cnt + g * 32;
    _Float16* hGg = hG + (size_t)g * 2 * 32 * 512;
    __syncthreads();

    for (int t = 0; t < S; ++t) {
        f32x4 acc[2][2];
#pragma unroll
        for (int mi = 0; mi < 2; mi++)
#pragma unroll
            for (int ni = 0; ni < 2; ni++) acc[mi][ni] = (f32x4){ bn[ni], bn[ni], bn[ni], bn[ni] };
#pragma unroll
        for (int kk = 0; kk < 12; kk++) {
            half8 ah[2], al[2];
#pragma unroll
            for (int mi = 0; mi < 2; mi++) {
                int row = mi * 16 + l15;
                int swz = (row & 7) << 4;
                if (kk < 4) {
                    int byte = ((kk * 32 + l4 * 8) * 2) ^ swz;
                    ah[mi] = *(const half8*)((const char*)(Ah + row * 384) + byte);
                } else {
                    int jb = ((kk - 4) * 32 + l4 * 8) * 2;
                    ah[mi] = *(const half8*)((const char*)(Ah + row * 384) + 256 + (jb ^ swz));
                    al[mi] = *(const half8*)((const char*)(Al + row * 256) + (jb ^ swz));
                }
            }
#pragma unroll
            for (int mi = 0; mi < 2; mi++)
#pragma unroll
                for (int ni = 0; ni < 2; ni++) {
                    acc[mi][ni] = __builtin_amdgcn_mfma_f32_16x16x32_f16(ah[mi], bwh[kk][ni], acc[mi][ni], 0, 0, 0);
                    if (kk >= 4) {
                        acc[mi][ni] = __builtin_amdgcn_mfma_f32_16x16x32_f16(ah[mi], bwlo[kk - 4][ni], acc[mi][ni], 0, 0, 0);
                        acc[mi][ni] = __builtin_amdgcn_mfma_f32_16x16x32_f16(al[mi], bwh[kk][ni], acc[mi][ni], 0, 0, 0);
                    }
                }
        }
        half8 xp0 = {}, xp1 = {};
        if (t < S - 1) {
            const _Float16* src = xtr16 + (((size_t)L * B + b0 + b_pw) * S + (t + 1)) * 128 + jq * 16;
            xp0 = *(const half8*)src;
            xp1 = *(const half8*)(src + 8);
        }
#pragma unroll
        for (int mi = 0; mi < 2; mi++)
#pragma unroll
            for (int ni = 0; ni < 2; ni++)
#pragma unroll
                for (int r = 0; r < 4; r++)
                    gl[mi * 16 + l4 * 4 + r][w * 32 + ni * 16 + l15] = acc[mi][ni][r];
        __syncthreads();   // B1
        {
            f32x4 iv = *(const f32x4*)&gl[b_pw][0 + jq * 4];
            f32x4 fv = *(const f32x4*)&gl[b_pw][32 + jq * 4];
            f32x4 gv = *(const f32x4*)&gl[b_pw][64 + jq * 4];
            f32x4 ov = *(const f32x4*)&gl[b_pw][96 + jq * 4];
            float hv[4];
            _Float16 hh[4], hl[4];
#pragma unroll
            for (int q = 0; q < 4; q++) {
                float cc = sigm(fv[q]) * cst[q] + sigm(iv[q]) * tanh_fast(gv[q]);
                cst[q] = cc;
                hv[q] = sigm(ov[q]) * tanh_fast(cc);
                hh[q] = (_Float16)hv[q];
                hl[q] = (_Float16)(hv[q] - (float)hh[q]);
            }
            size_t hidx = (((size_t)L * B + b0 + b_pw) * S + t) * H + sC * 32 + jq * 4;
            if constexpr (sizeof(HT) == 4) {
                *(float4*)((float*)hs + hidx) = make_float4(hv[0], hv[1], hv[2], hv[3]);
            } else {
                half4v h4 = { hh[0], hh[1], hh[2], hh[3] };
                *(half4v*)((_Float16*)hs + hidx) = h4;
            }
            if (t < S - 1) {
                int par = t & 1;
                _Float16* dsth = hGg + par * 32 * 512 + b_pw * 512 + sC * 32 + jq * 4;
                *(half4v*)dsth = *(half4v*)hh;
                *(half4v*)(dsth + 256) = *(half4v*)hl;
                int bswz = (b_pw & 7) << 4;
                *(half8*)((char*)(Ah + b_pw * 384) + ((jq * 32) ^ bswz)) = xp0;
                *(half8*)((char*)(Ah + b_pw * 384) + ((jq * 32 + 16) ^ bswz)) = xp1;
            }
        }
        if (t < S - 1) {
            __syncthreads();   // B2
            if (tid == 0) {
                __hip_atomic_fetch_add(mycnt, 1u, __ATOMIC_RELEASE, __HIP_MEMORY_SCOPE_AGENT);
                unsigned int target = 8u * (unsigned)(t + 1);
                while (__hip_atomic_load(mycnt, __ATOMIC_RELAXED, __HIP_MEMORY_SCOPE_AGENT) < target)
                    __builtin_amdgcn_s_sleep(1);
            }
            __syncthreads();   // B3
            __builtin_amdgcn_fence(__ATOMIC_ACQUIRE, "agent");
            {
                int par = t & 1;
                const _Float16* srch = hGg + par * 32 * 512 + b_pw * 512 + jq * 32;
                int bswz = (b_pw & 7) << 4;
#pragma unroll
                for (int u = 0; u < 4; u++) {
                    half8 vh = *(const half8*)(srch + u * 8);
                    half8 vl = *(const half8*)(srch + 256 + u * 8);
                    int jb = (jq * 32 + u * 8) * 2;
                    *(half8*)((char*)(Ah + b_pw * 384) + 256 + (jb ^ bswz)) = vh;
                    *(half8*)((char*)(Al + b_pw * 256) + (jb ^ bswz)) = vl;
                }
            }
            __syncthreads();   // B4
        }
    }
}

// ---------------- attention context ----------------
template<typename HT>
__global__ __launch_bounds__(256) void attn_ctx_kernel(const HT* __restrict__ hs_s, const HT* __restrict__ hs_m,
                                                       float* __restrict__ ctx_s, float* __restrict__ ctx_m)
{
    const int b = blockIdx.x;
    const int L = blockIdx.y;
    const HT* hsb = (L ? hs_m : hs_s) + (size_t)b * S * H;
    float* ctx = (L ? ctx_m : ctx_s) + b * H;
    const int tid = threadIdx.x;

    __shared__ float hlast[H];
    __shared__ float dist[S];
    __shared__ float red[4];

    hlast[tid] = cvtf(hsb[(size_t)(S - 1) * H + tid]);
    __syncthreads();

    float s = 0.f;
    {
        const HT* row = hsb + (size_t)tid * H;
        if constexpr (sizeof(HT) == 2) {
            const half8* r8 = (const half8*)row;
#pragma unroll 4
            for (int c = 0; c < H / 8; ++c) {
                half8 v = r8[c];
#pragma unroll
                for (int j = 0; j < 8; j++) s = fmaf((float)v[j], hlast[c * 8 + j], s);
            }
        } else {
            const float4* r4 = (const float4*)row;
#pragma unroll 4
            for (int c = 0; c < H / 4; ++c) {
                float4 v = r4[c];
                s = fmaf(v.x, hlast[c * 4 + 0], s);
                s = fmaf(v.y, hlast[c * 4 + 1], s);
                s = fmaf(v.z, hlast[c * 4 + 2], s);
                s = fmaf(v.w, hlast[c * 4 + 3], s);
            }
        }
    }
    float v = s;
    for (int o = 32; o > 0; o >>= 1) v += __shfl_down(v, o);
    if ((tid & 63) == 0) red[tid >> 6] = v;
    __syncthreads();
    float denom = red[0] + red[1] + red[2] + red[3];
    dist[tid] = s / denom;
    __syncthreads();

    float acc = 0.f;
    for (int t = 0; t < S; ++t) acc = fmaf(dist[t], cvtf(hsb[(size_t)t * H + tid]), acc);
    ctx[tid] = acc;
}

// ---------------- tail ----------------
__global__ __launch_bounds__(256) void tail_kernel(
    const float* __restrict__ ctx_s, const float* __restrict__ ctx_m,
    const float* __restrict__ norm_w, const float* __restrict__ norm_b,
    const float* __restrict__ macro_w,
    const float* __restrict__ in_w, const float* __restrict__ in_b,
    const float* __restrict__ outp_w, const float* __restrict__ outp_b,
    const float* __restrict__ w1, const float* __restrict__ b1,
    const float* __restrict__ w2, const float* __restrict__ b2,
    const float* __restrict__ fw, const float* __restrict__ fb,
    float* __restrict__ out)
{
    const int b = blockIdx.x;
    const int tid = threadIdx.x;

    __shared__ float ml[NS][H];
    __shared__ float buf[NS][H];
    __shared__ float qh[NS][DH], kh[NS][DH], vh[NS][DH], sc[NS][NS];
    __shared__ float red[4];

    float cs = ctx_s[b * H + tid];
    float v = cs;
    for (int o = 32; o > 0; o >>= 1) v += __shfl_down(v, o);
    if ((tid & 63) == 0) red[tid >> 6] = v;
    __syncthreads();
    float mean = (red[0] + red[1] + red[2] + red[3]) * (1.f / H);
    float dv = cs - mean;
    __syncthreads();
    v = dv * dv;
    for (int o = 32; o > 0; o >>= 1) v += __shfl_down(v, o);
    if ((tid & 63) == 0) red[tid >> 6] = v;
    __syncthreads();
    float stdv = sqrtf((red[0] + red[1] + red[2] + red[3]) * (1.f / (H - 1))) + 1e-8f;
    float z = dv / stdv;
    float cm = ctx_m[b * H + tid];
    float mwv = macro_w[0];
    for (int n = 0; n < NS; ++n)
        ml[n][tid] = norm_w[n * H + tid] * z + norm_b[n * H + tid] + mwv * cm;
    __syncthreads();

    const int dloc = tid & 31;
    const int iset = tid >> 5;
    const float scale = 0.17677669529663687f;
    for (int h = 0; h < NH; ++h) {
        {
            int rq = h * DH + dloc;
            int rk = H + h * DH + dloc;
            int rv = 2 * H + h * DH + dloc;
            float aq[4], ak[4], av[4];
#pragma unroll
            for (int r = 0; r < 4; r++) { aq[r] = in_b[rq]; ak[r] = in_b[rk]; av[r] = in_b[rv]; }
            for (int k = 0; k < H; ++k) {
                float wq = in_w[rq * H + k];
                float wk = in_w[rk * H + k];
                float wv = in_w[rv * H + k];
#pragma unroll
                for (int r = 0; r < 4; r++) {
                    float m = ml[iset + 8 * r][k];
                    aq[r] = fmaf(m, wq, aq[r]); ak[r] = fmaf(m, wk, ak[r]); av[r] = fmaf(m, wv, av[r]);
                }
            }
#pragma unroll
            for (int r = 0; r < 4; r++) { qh[iset + 8 * r][dloc] = aq[r]; kh[iset + 8 * r][dloc] = ak[r]; vh[iset + 8 * r][dloc] = av[r]; }
        }
        __syncthreads();
        {
            int i = tid >> 3;
            int j0 = (tid & 7) * 4;
            float a[4] = { 0.f, 0.f, 0.f, 0.f };
            for (int d = 0; d < DH; ++d) {
                float q = qh[i][d];
#pragma unroll
                for (int jj = 0; jj < 4; jj++) a[jj] = fmaf(q, kh[j0 + jj][d], a[jj]);
            }
#pragma unroll
            for (int jj = 0; jj < 4; jj++) sc[i][j0 + jj] = a[jj] * scale;
        }
        __syncthreads();
        if (tid < NS) {
            float mx = -1e30f;
            for (int j = 0; j < NS; j++) mx = fmaxf(mx, sc[tid][j]);
            float sm = 0.f, e[NS];
            for (int j = 0; j < NS; j++) { e[j] = __expf(sc[tid][j] - mx); sm += e[j]; }
            float inv = 1.f / sm;
            for (int j = 0; j < NS; j++) sc[tid][j] = e[j] * inv;
        }
        __syncthreads();
        {
            int i = tid >> 3;
            int d0 = (tid & 7) * 4;
            float a[4] = { 0.f, 0.f, 0.f, 0.f };
            for (int j = 0; j < NS; ++j) {
                float sv = sc[i][j];
#pragma unroll
                for (int dd = 0; dd < 4; dd++) a[dd] = fmaf(sv, vh[j][d0 + dd], a[dd]);
            }
#pragma unroll
            for (int dd = 0; dd < 4; dd++) buf[i][h * DH + d0 + dd] = a[dd];
        }
        __syncthreads();
    }

    {
        float acc32[NS];
        float ob = outp_b[tid];
#pragma unroll
        for (int t = 0; t < NS; t++) acc32[t] = ob;
        for (int k = 0; k < H; ++k) {
            float w = outp_w[tid * H + k];
#pragma unroll
            for (int t = 0; t < NS; t++) acc32[t] = fmaf(buf[t][k], w, acc32[t]);
        }
#pragma unroll
        for (int t = 0; t < NS; t++) ml[t][tid] += acc32[t];
    }
    __syncthreads();

    float acc_o[NS];
    {
        float b2v = b2[tid];
#pragma unroll
        for (int t = 0; t < NS; t++) acc_o[t] = b2v;
    }
    for (int jc = 0; jc < 4; ++jc) {
        float hid[NS];
        {
            float b1v = b1[jc * H + tid];
#pragma unroll
            for (int t = 0; t < NS; t++) hid[t] = b1v;
            for (int k = 0; k < H; ++k) {
                float w = w1[(size_t)(jc * H + tid) * H + k];
#pragma unroll
                for (int t = 0; t < NS; t++) hid[t] = fmaf(ml[t][k], w, hid[t]);
            }
        }
        __syncthreads();
#pragma unroll
        for (int t = 0; t < NS; t++) buf[t][tid] = fmaxf(hid[t], 0.f);
        __syncthreads();
        for (int k = 0; k < H; ++k) {
            float w = w2[(size_t)tid * G4 + jc * H + k];
#pragma unroll
            for (int t = 0; t < NS; t++) acc_o[t] = fmaf(buf[t][k], w, acc_o[t]);
        }
        __syncthreads();
    }

    float p = 0.f;
#pragma unroll
    for (int t = 0; t < NS; t++) p += tanhf(ml[t][tid] + acc_o[t]);
    p *= (1.f / NS);
    v = p * fw[tid];
    for (int o = 32; o > 0; o >>= 1) v += __shfl_down(v, o);
    if ((tid & 63) == 0) red[tid >> 6] = v;
    __syncthreads();
    if (tid == 0) out[b] = red[0] + red[1] + red[2] + red[3] + fb[0];
}

// ---------------- host ----------------
extern "C" void kernel_launch(void* const* d_in, const int* in_sizes, int n_in,
                              void* d_out, int out_size, void* d_ws, size_t ws_size,
                              hipStream_t stream) {
    const float* x      = (const float*)d_in[0];
    const float* stw    = (const float*)d_in[1];
    const float* stb    = (const float*)d_in[2];
    const float* mtw    = (const float*)d_in[3];
    const float* mtb    = (const float*)d_in[4];
    const float* s_wih  = (const float*)d_in[5];
    const float* s_whh  = (const float*)d_in[6];
    const float* s_bih  = (const float*)d_in[7];
    const float* s_bhh  = (const float*)d_in[8];
    const float* m_wih  = (const float*)d_in[9];
    const float* m_whh  = (const float*)d_in[10];
    const float* m_bih  = (const float*)d_in[11];
    const float* m_bhh  = (const float*)d_in[12];
    const float* norm_w = (const float*)d_in[13];
    const float* norm_b = (const float*)d_in[14];
    const float* macro_w= (const float*)d_in[15];
    const float* in_w   = (const float*)d_in[16];
    const float* in_b   = (const float*)d_in[17];
    const float* outp_w = (const float*)d_in[18];
    const float* outp_b = (const float*)d_in[19];
    const float* w1     = (const float*)d_in[20];
    const float* b1     = (const float*)d_in[21];
    const float* w2     = (const float*)d_in[22];
    const float* b2     = (const float*)d_in[23];
    const float* fw     = (const float*)d_in[24];
    const float* fb     = (const float*)d_in[25];
    float* out = (float*)d_out;

    // workspace layout (256B-aligned blocks)
    size_t off = 0;
    auto alloc = [&](size_t bytes) { char* q = (char*)d_ws + off; off += (bytes + 255) & ~(size_t)255; return q; };
    _Float16* W16h  = (_Float16*)alloc((size_t)2 * 8 * 128 * 384 * 2);
    _Float16* W16l  = (_Float16*)alloc((size_t)2 * 8 * 128 * 256 * 2);
    float*    biasP = (float*)alloc((size_t)2 * 8 * 128 * 4);
    _Float16* trW16 = (_Float16*)alloc((size_t)256 * 128 * 2);
    _Float16* hG    = (_Float16*)alloc((size_t)32 * 2 * 32 * 512 * 2);
    unsigned int* cnt = (unsigned int*)alloc(4096);
    float*    ctx_s = (float*)alloc((size_t)B * H * 4);
    float*    ctx_m = (float*)alloc((size_t)B * H * 4);
    _Float16* xtr16 = (_Float16*)alloc((size_t)2 * B * S * 128 * 2);   // 64 MiB
    size_t off_before_hs = off;
    const size_t hs_elems = (size_t)2 * B * S * H;                     // both LSTMs
    const size_t need_full = off_before_hs + hs_elems * sizeof(float) + (1u << 20);
    const bool f32hs = ws_size >= need_full;

    prep_kernel<<<128, 256, 0, stream>>>(s_wih, s_whh, s_bih, s_bhh,
                                         m_wih, m_whh, m_bih, m_bhh,
                                         stw, mtw, W16h, W16l, biasP, trW16);
    xtr_kernel<<<B, 256, 0, stream>>>(x, trW16, stb, mtb, xtr16);
    (void)hipMemsetAsync(cnt, 0, 4096, stream);

    if (f32hs) {
        float* hs = (float*)alloc(hs_elems * sizeof(float));
        lstm_mfma<float><<<256, 256, 0, stream>>>(W16h, W16l, biasP, xtr16, hs, hG, cnt);
        attn_ctx_kernel<float><<<dim3(B, 2), 256, 0, stream>>>(hs, hs + hs_elems / 2, ctx_s, ctx_m);
    } else {
        _Float16* hs = (_Float16*)alloc(hs_elems * sizeof(_Float16));
        lstm_mfma<_Float16><<<256, 256, 0, stream>>>(W16h, W16l, biasP, xtr16, hs, hG, cnt);
        attn_ctx_kernel<_Float16><<<dim3(B, 2), 256, 0, stream>>>(hs, hs + hs_elems / 2, ctx_s, ctx_m);
    }

    tail_kernel<<<B, 256, 0, stream>>>(ctx_s, ctx_m,
                                       norm_w, norm_b, macro_w,
                                       in_w, in_b, outp_w, outp_b,
                                       w1, b1, w2, b2, fw, fb, out);
}

// Round 5
// 2323.564 us; speedup vs baseline: 5.5298x; 2.3220x over previous
//
#include <hip/hip_runtime.h>
#include <hip/hip_bf16.h>
#include <math.h>

#define B 512
#define S 256
#define D 128
#define H 256
#define G4 1024
#define NS 32
#define NH 8
#define DH 32

typedef _Float16 half8 __attribute__((ext_vector_type(8)));
typedef _Float16 half4v __attribute__((ext_vector_type(4)));
typedef float f32x4 __attribute__((ext_vector_type(4)));

__device__ __forceinline__ float sigm(float v) { return 1.f / (1.f + __expf(-v)); }
__device__ __forceinline__ float tanh_fast(float x) { float e = __expf(2.f * x); return 1.f - 2.f / (e + 1.f); }
__device__ __forceinline__ float cvtf(float v) { return v; }
__device__ __forceinline__ float cvtf(_Float16 v) { return (float)v; }

// ---------------- prep: fp16 weight slices in MFMA-friendly [n][k] layout ----------------
__global__ void prep_kernel(const float* __restrict__ s_wih, const float* __restrict__ s_whh,
                            const float* __restrict__ s_bih, const float* __restrict__ s_bhh,
                            const float* __restrict__ m_wih, const float* __restrict__ m_whh,
                            const float* __restrict__ m_bih, const float* __restrict__ m_bhh,
                            const float* __restrict__ stw, const float* __restrict__ mtw,
                            _Float16* __restrict__ W16h, _Float16* __restrict__ W16l,
                            float* __restrict__ biasP, _Float16* __restrict__ trW16)
{
    int tid = blockIdx.x * blockDim.x + threadIdx.x;
    int stride = gridDim.x * blockDim.x;
    for (int i = tid; i < 2 * 8 * 128 * 384; i += stride) {
        int k = i % 384; int n = (i / 384) % 128; int c = (i / (384 * 128)) % 8; int L = i / (384 * 128 * 8);
        int row = (n >> 5) * 256 + c * 32 + (n & 31);
        const float* wih = L ? m_wih : s_wih;
        const float* whh = L ? m_whh : s_whh;
        float v = (k < 128) ? wih[row * 128 + k] : whh[row * 256 + (k - 128)];
        W16h[i] = (_Float16)v;
    }
    for (int i = tid; i < 2 * 8 * 128 * 256; i += stride) {
        int k = i % 256; int n = (i / 256) % 128; int c = (i / (256 * 128)) % 8; int L = i / (256 * 128 * 8);
        int row = (n >> 5) * 256 + c * 32 + (n & 31);
        const float* whh = L ? m_whh : s_whh;
        float v = whh[row * 256 + k];
        _Float16 hi = (_Float16)v;
        W16l[i] = (_Float16)(v - (float)hi);
    }
    for (int i = tid; i < 2 * 8 * 128; i += stride) {
        int n = i % 128; int c = (i / 128) % 8; int L = i / (128 * 8);
        int row = (n >> 5) * 256 + c * 32 + (n & 31);
        biasP[i] = L ? (m_bih[row] + m_bhh[row]) : (s_bih[row] + s_bhh[row]);
    }
    for (int i = tid; i < 256 * 128; i += stride) {
        int k = i % 128, n = i / 128;
        trW16[i] = (_Float16)(n < 128 ? stw[n * 128 + k] : mtw[(n - 128) * 128 + k]);
    }
}

// ---------------- xtr: xtr16[L][b][t][d] = fp16(tanh(x @ trW^T + trb)), MFMA ----------------
__global__ __launch_bounds__(256, 1) void xtr_kernel(const float* __restrict__ x,
        const _Float16* __restrict__ trW16,
        const float* __restrict__ stb, const float* __restrict__ mtb,
        _Float16* __restrict__ xtr16)
{
    const int b = blockIdx.x;
    const int tid = threadIdx.x;
    const int w = tid >> 6, l = tid & 63, l15 = l & 15, l4 = l >> 4;

    __shared__ _Float16 xa[128 * 128];

    half8 bw[4][4];
#pragma unroll
    for (int kk = 0; kk < 4; kk++)
#pragma unroll
        for (int ni = 0; ni < 4; ni++)
            bw[kk][ni] = *(const half8*)(trW16 + (w * 64 + ni * 16 + l15) * 128 + kk * 32 + l4 * 8);
    float tb[4];
#pragma unroll
    for (int ni = 0; ni < 4; ni++) { int d = w * 64 + ni * 16 + l15; tb[ni] = d < 128 ? stb[d] : mtb[d - 128]; }

    for (int h2 = 0; h2 < 2; ++h2) {
        {
            int trow = tid >> 1, seg = tid & 1;
            const float* src = x + ((size_t)b * S + h2 * 128 + trow) * 128 + seg * 64;
            int swz = (trow & 7) << 4;
#pragma unroll
            for (int q8 = 0; q8 < 8; q8++) {
                float4 f0 = *(const float4*)(src + q8 * 8);
                float4 f1 = *(const float4*)(src + q8 * 8 + 4);
                half8 hv = { (_Float16)f0.x, (_Float16)f0.y, (_Float16)f0.z, (_Float16)f0.w,
                             (_Float16)f1.x, (_Float16)f1.y, (_Float16)f1.z, (_Float16)f1.w };
                int byte = ((seg * 64 + q8 * 8) * 2) ^ swz;
                *(half8*)((char*)(xa + trow * 128) + byte) = hv;
            }
        }
        __syncthreads();
        for (int mt = 0; mt < 8; ++mt) {
            int row = mt * 16 + l15;
            int swz = (row & 7) << 4;
            half8 af[4];
#pragma unroll
            for (int kk = 0; kk < 4; kk++) {
                int byte = ((kk * 32 + l4 * 8) * 2) ^ swz;
                af[kk] = *(const half8*)((const char*)(xa + row * 128) + byte);
            }
            f32x4 acc[4];
#pragma unroll
            for (int ni = 0; ni < 4; ni++) acc[ni] = (f32x4){ tb[ni], tb[ni], tb[ni], tb[ni] };
#pragma unroll
            for (int kk = 0; kk < 4; kk++)
#pragma unroll
                for (int ni = 0; ni < 4; ni++)
                    acc[ni] = __builtin_amdgcn_mfma_f32_16x16x32_f16(af[kk], bw[kk][ni], acc[ni], 0, 0, 0);
#pragma unroll
            for (int ni = 0; ni < 4; ni++) {
                int d = w * 64 + ni * 16 + l15;
                int Ls = d >> 7, dl = d & 127;
#pragma unroll
                for (int r = 0; r < 4; r++) {
                    int t = h2 * 128 + mt * 16 + l4 * 4 + r;
                    xtr16[(((size_t)Ls * B + b) * S + t) * 128 + dl] = (_Float16)tanh_fast(acc[ni][r]);
                }
            }
        }
        __syncthreads();
    }
}

// ---------------- persistent MFMA LSTM, L3-coherent flag sync (no L2 flush) ----------------
template<typename HT>
__global__ __launch_bounds__(256, 1) void lstm_mfma(
    const _Float16* __restrict__ W16h, const _Float16* __restrict__ W16l,
    const float* __restrict__ biasP,
    const _Float16* __restrict__ xtr16,
    HT* __restrict__ hs, _Float16* __restrict__ hG, unsigned int* __restrict__ flags)
{
    const int bid = blockIdx.x;
    const int sC = bid >> 5;
    const int g = bid & 31;
    const int L = g >> 4;
    const int bt = g & 15;
    const int b0 = bt * 32;
    const int tid = threadIdx.x;
    const int w = tid >> 6, l = tid & 63, l15 = l & 15, l4 = l >> 4;

    __shared__ _Float16 Ah[32 * 384];
    __shared__ _Float16 Al[32 * 256];
    __shared__ float gl[32][132];

    for (int i = tid; i < 32 * 384 * 2 / 16; i += 256) ((int4*)Ah)[i] = make_int4(0, 0, 0, 0);
    for (int i = tid; i < 32 * 256 * 2 / 16; i += 256) ((int4*)Al)[i] = make_int4(0, 0, 0, 0);

    const size_t wbh = ((size_t)(L * 8 + sC) * 128) * 384;
    const size_t wbl = ((size_t)(L * 8 + sC) * 128) * 256;
    half8 bwh[12][2], bwlo[8][2];
#pragma unroll
    for (int kk = 0; kk < 12; kk++)
#pragma unroll
        for (int ni = 0; ni < 2; ni++)
            bwh[kk][ni] = *(const half8*)(W16h + wbh + (size_t)(w * 32 + ni * 16 + l15) * 384 + kk * 32 + l4 * 8);
#pragma unroll
    for (int kk = 0; kk < 8; kk++)
#pragma unroll
        for (int ni = 0; ni < 2; ni++)
            bwlo[kk][ni] = *(const half8*)(W16l + wbl + (size_t)(w * 32 + ni * 16 + l15) * 256 + kk * 32 + l4 * 8);
    float bn[2];
#pragma unroll
    for (int ni = 0; ni < 2; ni++) bn[ni] = biasP[(L * 8 + sC) * 128 + w * 32 + ni * 16 + l15];

    const int b_pw = tid >> 3, jq = tid & 7;
    {
        const _Float16* src = xtr16 + (((size_t)L * B + b0 + b_pw) * S + 0) * 128 + jq * 16;
        half8 v0 = *(const half8*)src;
        half8 v1 = *(const half8*)(src + 8);
        int bswz = (b_pw & 7) << 4;
        *(half8*)((char*)(Ah + b_pw * 384) + ((jq * 32) ^ bswz)) = v0;
        *(half8*)((char*)(Ah + b_pw * 384) + ((jq * 32 + 16) ^ bswz)) = v1;
    }
    float cst[4] = { 0.f, 0.f, 0.f, 0.f };
    _Float16* hGg = hG + (size_t)g * 2 * 32 * 512;
    __syncthreads();

    for (int t = 0; t < S; ++t) {
        f32x4 acc[2][2];
#pragma unroll
        for (int mi = 0; mi < 2; mi++)
#pragma unroll
            for (int ni = 0; ni < 2; ni++) acc[mi][ni] = (f32x4){ bn[ni], bn[ni], bn[ni], bn[ni] };
#pragma unroll
        for (int kk = 0; kk < 12; kk++) {
            half8 ah[2], al[2];
#pragma unroll
            for (int mi = 0; mi < 2; mi++) {
                int row = mi * 16 + l15;
                int swz = (row & 7) << 4;
                if (kk < 4) {
                    int byte = ((kk * 32 + l4 * 8) * 2) ^ swz;
                    ah[mi] = *(const half8*)((const char*)(Ah + row * 384) + byte);
                } else {
                    int jb = ((kk - 4) * 32 + l4 * 8) * 2;
                    ah[mi] = *(const half8*)((const char*)(Ah + row * 384) + 256 + (jb ^ swz));
                    al[mi] = *(const half8*)((const char*)(Al + row * 256) + (jb ^ swz));
                }
            }
#pragma unroll
            for (int mi = 0; mi < 2; mi++)
#pragma unroll
                for (int ni = 0; ni < 2; ni++) {
                    acc[mi][ni] = __builtin_amdgcn_mfma_f32_16x16x32_f16(ah[mi], bwh[kk][ni], acc[mi][ni], 0, 0, 0);
                    if (kk >= 4) {
                        acc[mi][ni] = __builtin_amdgcn_mfma_f32_16x16x32_f16(ah[mi], bwlo[kk - 4][ni], acc[mi][ni], 0, 0, 0);
                        acc[mi][ni] = __builtin_amdgcn_mfma_f32_16x16x32_f16(al[mi], bwh[kk][ni], acc[mi][ni], 0, 0, 0);
                    }
                }
        }
        half8 xp0 = {}, xp1 = {};
        if (t < S - 1) {
            const _Float16* src = xtr16 + (((size_t)L * B + b0 + b_pw) * S + (t + 1)) * 128 + jq * 16;
            xp0 = *(const half8*)src;
            xp1 = *(const half8*)(src + 8);
        }
#pragma unroll
        for (int mi = 0; mi < 2; mi++)
#pragma unroll
            for (int ni = 0; ni < 2; ni++)
#pragma unroll
                for (int r = 0; r < 4; r++)
                    gl[mi * 16 + l4 * 4 + r][w * 32 + ni * 16 + l15] = acc[mi][ni][r];
        __syncthreads();   // B1: gates visible
        {
            f32x4 iv = *(const f32x4*)&gl[b_pw][0 + jq * 4];
            f32x4 fv = *(const f32x4*)&gl[b_pw][32 + jq * 4];
            f32x4 gv = *(const f32x4*)&gl[b_pw][64 + jq * 4];
            f32x4 ov = *(const f32x4*)&gl[b_pw][96 + jq * 4];
            float hv[4];
            _Float16 hh[4], hl[4];
#pragma unroll
            for (int q = 0; q < 4; q++) {
                float cc = sigm(fv[q]) * cst[q] + sigm(iv[q]) * tanh_fast(gv[q]);
                cst[q] = cc;
                hv[q] = sigm(ov[q]) * tanh_fast(cc);
                hh[q] = (_Float16)hv[q];
                hl[q] = (_Float16)(hv[q] - (float)hh[q]);
            }
            size_t hidx = (((size_t)L * B + b0 + b_pw) * S + t) * H + sC * 32 + jq * 4;
            if constexpr (sizeof(HT) == 4) {
                *(float4*)((float*)hs + hidx) = make_float4(hv[0], hv[1], hv[2], hv[3]);
            } else {
                half4v h4 = { hh[0], hh[1], hh[2], hh[3] };
                *(half4v*)((_Float16*)hs + hidx) = h4;
            }
            if (t < S - 1) {
                int par = t & 1;
                _Float16* dsth = hGg + par * 32 * 512 + b_pw * 512 + sC * 32 + jq * 4;
                half4v dhi = { hh[0], hh[1], hh[2], hh[3] };
                half4v dlo = { hl[0], hl[1], hl[2], hl[3] };
                // device-coherent (L3) stores: bypass non-coherent per-XCD L2
                asm volatile("global_store_dwordx2 %0, %1, off sc0 sc1" :: "v"(dsth), "v"(dhi) : "memory");
                asm volatile("global_store_dwordx2 %0, %1, off sc0 sc1" :: "v"(dsth + 256), "v"(dlo) : "memory");
                int bswz = (b_pw & 7) << 4;
                *(half8*)((char*)(Ah + b_pw * 384) + ((jq * 32) ^ bswz)) = xp0;
                *(half8*)((char*)(Ah + b_pw * 384) + ((jq * 32 + 16) ^ bswz)) = xp1;
            }
        }
        if (t < S - 1) {
            // drain own dc-stores (inline-asm ops are invisible to compiler waitcnt tracking)
            asm volatile("s_waitcnt vmcnt(0)" ::: "memory");
            __syncthreads();   // B2: all threads' h-chunk stores are at L3
            if (tid == 0) {
                unsigned int one = 1u;
                const unsigned int* fp = flags + (((unsigned)g * 256u + (unsigned)t) * 8u + (unsigned)sC);
                asm volatile("global_store_dword %0, %1, off sc0 sc1" :: "v"(fp), "v"(one) : "memory");
            }
            // each thread depends only on writer sC == jq: poll that flag directly
            {
                const unsigned int* fp = flags + (((unsigned)g * 256u + (unsigned)t) * 8u + (unsigned)jq);
                unsigned int v;
                while (true) {
                    asm volatile("global_load_dword %0, %1, off sc0 sc1\n\ts_waitcnt vmcnt(0)"
                                 : "=v"(v) : "v"(fp) : "memory");
                    if (v) break;
                    __builtin_amdgcn_s_sleep(2);
                }
            }
            {
                int par = t & 1;
                const _Float16* srch = hGg + par * 32 * 512 + b_pw * 512 + jq * 32;
                half8 vh[4], vl[4];
#pragma unroll
                for (int u = 0; u < 4; u++) {
                    asm volatile("global_load_dwordx4 %0, %1, off sc0 sc1" : "=v"(vh[u]) : "v"(srch + u * 8) : "memory");
                    asm volatile("global_load_dwordx4 %0, %1, off sc0 sc1" : "=v"(vl[u]) : "v"(srch + 256 + u * 8) : "memory");
                }
                asm volatile("s_waitcnt vmcnt(0)" ::: "memory");
                __builtin_amdgcn_sched_barrier(0);
                int bswz = (b_pw & 7) << 4;
#pragma unroll
                for (int u = 0; u < 4; u++) {
                    int jb = (jq * 32 + u * 8) * 2;
                    *(half8*)((char*)(Ah + b_pw * 384) + 256 + (jb ^ bswz)) = vh[u];
                    *(half8*)((char*)(Al + b_pw * 256) + (jb ^ bswz)) = vl[u];
                }
            }
            __syncthreads();   // B4: h ready for next step
        }
    }
}

// ---------------- attention context ----------------
template<typename HT>
__global__ __launch_bounds__(256) void attn_ctx_kernel(const HT* __restrict__ hs_s, const HT* __restrict__ hs_m,
                                                       float* __restrict__ ctx_s, float* __restrict__ ctx_m)
{
    const int b = blockIdx.x;
    const int L = blockIdx.y;
    const HT* hsb = (L ? hs_m : hs_s) + (size_t)b * S * H;
    float* ctx = (L ? ctx_m : ctx_s) + b * H;
    const int tid = threadIdx.x;

    __shared__ float hlast[H];
    __shared__ float dist[S];
    __shared__ float red[4];

    hlast[tid] = cvtf(hsb[(size_t)(S - 1) * H + tid]);
    __syncthreads();

    float s = 0.f;
    {
        const HT* row = hsb + (size_t)tid * H;
        if constexpr (sizeof(HT) == 2) {
            const half8* r8 = (const half8*)row;
#pragma unroll 4
            for (int c = 0; c < H / 8; ++c) {
                half8 v = r8[c];
#pragma unroll
                for (int j = 0; j < 8; j++) s = fmaf((float)v[j], hlast[c * 8 + j], s);
            }
        } else {
            const float4* r4 = (const float4*)row;
#pragma unroll 4
            for (int c = 0; c < H / 4; ++c) {
                float4 v = r4[c];
                s = fmaf(v.x, hlast[c * 4 + 0], s);
                s = fmaf(v.y, hlast[c * 4 + 1], s);
                s = fmaf(v.z, hlast[c * 4 + 2], s);
                s = fmaf(v.w, hlast[c * 4 + 3], s);
            }
        }
    }
    float v = s;
    for (int o = 32; o > 0; o >>= 1) v += __shfl_down(v, o);
    if ((tid & 63) == 0) red[tid >> 6] = v;
    __syncthreads();
    float denom = red[0] + red[1] + red[2] + red[3];
    dist[tid] = s / denom;
    __syncthreads();

    float acc = 0.f;
    for (int t = 0; t < S; ++t) acc = fmaf(dist[t], cvtf(hsb[(size_t)t * H + tid]), acc);
    ctx[tid] = acc;
}

// ---------------- tail ----------------
__global__ __launch_bounds__(256) void tail_kernel(
    const float* __restrict__ ctx_s, const float* __restrict__ ctx_m,
    const float* __restrict__ norm_w, const float* __restrict__ norm_b,
    const float* __restrict__ macro_w,
    const float* __restrict__ in_w, const float* __restrict__ in_b,
    const float* __restrict__ outp_w, const float* __restrict__ outp_b,
    const float* __restrict__ w1, const float* __restrict__ b1,
    const float* __restrict__ w2, const float* __restrict__ b2,
    const float* __restrict__ fw, const float* __restrict__ fb,
    float* __restrict__ out)
{
    const int b = blockIdx.x;
    const int tid = threadIdx.x;

    __shared__ float ml[NS][H];
    __shared__ float buf[NS][H];
    __shared__ float qh[NS][DH], kh[NS][DH], vh[NS][DH], sc[NS][NS];
    __shared__ float red[4];

    float cs = ctx_s[b * H + tid];
    float v = cs;
    for (int o = 32; o > 0; o >>= 1) v += __shfl_down(v, o);
    if ((tid & 63) == 0) red[tid >> 6] = v;
    __syncthreads();
    float mean = (red[0] + red[1] + red[2] + red[3]) * (1.f / H);
    float dv = cs - mean;
    __syncthreads();
    v = dv * dv;
    for (int o = 32; o > 0; o >>= 1) v += __shfl_down(v, o);
    if ((tid & 63) == 0) red[tid >> 6] = v;
    __syncthreads();
    float stdv = sqrtf((red[0] + red[1] + red[2] + red[3]) * (1.f / (H - 1))) + 1e-8f;
    float z = dv / stdv;
    float cm = ctx_m[b * H + tid];
    float mwv = macro_w[0];
    for (int n = 0; n < NS; ++n)
        ml[n][tid] = norm_w[n * H + tid] * z + norm_b[n * H + tid] + mwv * cm;
    __syncthreads();

    const int dloc = tid & 31;
    const int iset = tid >> 5;
    const float scale = 0.17677669529663687f;
    for (int h = 0; h < NH; ++h) {
        {
            int rq = h * DH + dloc;
            int rk = H + h * DH + dloc;
            int rv = 2 * H + h * DH + dloc;
            float aq[4], ak[4], av[4];
#pragma unroll
            for (int r = 0; r < 4; r++) { aq[r] = in_b[rq]; ak[r] = in_b[rk]; av[r] = in_b[rv]; }
            for (int k = 0; k < H; ++k) {
                float wq = in_w[rq * H + k];
                float wk = in_w[rk * H + k];
                float wv = in_w[rv * H + k];
#pragma unroll
                for (int r = 0; r < 4; r++) {
                    float m = ml[iset + 8 * r][k];
                    aq[r] = fmaf(m, wq, aq[r]); ak[r] = fmaf(m, wk, ak[r]); av[r] = fmaf(m, wv, av[r]);
                }
            }
#pragma unroll
            for (int r = 0; r < 4; r++) { qh[iset + 8 * r][dloc] = aq[r]; kh[iset + 8 * r][dloc] = ak[r]; vh[iset + 8 * r][dloc] = av[r]; }
        }
        __syncthreads();
        {
            int i = tid >> 3;
            int j0 = (tid & 7) * 4;
            float a[4] = { 0.f, 0.f, 0.f, 0.f };
            for (int d = 0; d < DH; ++d) {
                float q = qh[i][d];
#pragma unroll
                for (int jj = 0; jj < 4; jj++) a[jj] = fmaf(q, kh[j0 + jj][d], a[jj]);
            }
#pragma unroll
            for (int jj = 0; jj < 4; jj++) sc[i][j0 + jj] = a[jj] * scale;
        }
        __syncthreads();
        if (tid < NS) {
            float mx = -1e30f;
            for (int j = 0; j < NS; j++) mx = fmaxf(mx, sc[tid][j]);
            float sm = 0.f, e[NS];
            for (int j = 0; j < NS; j++) { e[j] = __expf(sc[tid][j] - mx); sm += e[j]; }
            float inv = 1.f / sm;
            for (int j = 0; j < NS; j++) sc[tid][j] = e[j] * inv;
        }
        __syncthreads();
        {
            int i = tid >> 3;
            int d0 = (tid & 7) * 4;
            float a[4] = { 0.f, 0.f, 0.f, 0.f };
            for (int j = 0; j < NS; ++j) {
                float sv = sc[i][j];
#pragma unroll
                for (int dd = 0; dd < 4; dd++) a[dd] = fmaf(sv, vh[j][d0 + dd], a[dd]);
            }
#pragma unroll
            for (int dd = 0; dd < 4; dd++) buf[i][h * DH + d0 + dd] = a[dd];
        }
        __syncthreads();
    }

    {
        float acc32[NS];
        float ob = outp_b[tid];
#pragma unroll
        for (int t = 0; t < NS; t++) acc32[t] = ob;
        for (int k = 0; k < H; ++k) {
            float w = outp_w[tid * H + k];
#pragma unroll
            for (int t = 0; t < NS; t++) acc32[t] = fmaf(buf[t][k], w, acc32[t]);
        }
#pragma unroll
        for (int t = 0; t < NS; t++) ml[t][tid] += acc32[t];
    }
    __syncthreads();

    float acc_o[NS];
    {
        float b2v = b2[tid];
#pragma unroll
        for (int t = 0; t < NS; t++) acc_o[t] = b2v;
    }
    for (int jc = 0; jc < 4; ++jc) {
        float hid[NS];
        {
            float b1v = b1[jc * H + tid];
#pragma unroll
            for (int t = 0; t < NS; t++) hid[t] = b1v;
            for (int k = 0; k < H; ++k) {
                float w = w1[(size_t)(jc * H + tid) * H + k];
#pragma unroll
                for (int t = 0; t < NS; t++) hid[t] = fmaf(ml[t][k], w, hid[t]);
            }
        }
        __syncthreads();
#pragma unroll
        for (int t = 0; t < NS; t++) buf[t][tid] = fmaxf(hid[t], 0.f);
        __syncthreads();
        for (int k = 0; k < H; ++k) {
            float w = w2[(size_t)tid * G4 + jc * H + k];
#pragma unroll
            for (int t = 0; t < NS; t++) acc_o[t] = fmaf(buf[t][k], w, acc_o[t]);
        }
        __syncthreads();
    }

    float p = 0.f;
#pragma unroll
    for (int t = 0; t < NS; t++) p += tanhf(ml[t][tid] + acc_o[t]);
    p *= (1.f / NS);
    v = p * fw[tid];
    for (int o = 32; o > 0; o >>= 1) v += __shfl_down(v, o);
    if ((tid & 63) == 0) red[tid >> 6] = v;
    __syncthreads();
    if (tid == 0) out[b] = red[0] + red[1] + red[2] + red[3] + fb[0];
}

// ---------------- host ----------------
extern "C" void kernel_launch(void* const* d_in, const int* in_sizes, int n_in,
                              void* d_out, int out_size, void* d_ws, size_t ws_size,
                              hipStream_t stream) {
    const float* x      = (const float*)d_in[0];
    const float* stw    = (const float*)d_in[1];
    const float* stb    = (const float*)d_in[2];
    const float* mtw    = (const float*)d_in[3];
    const float* mtb    = (const float*)d_in[4];
    const float* s_wih  = (const float*)d_in[5];
    const float* s_whh  = (const float*)d_in[6];
    const float* s_bih  = (const float*)d_in[7];
    const float* s_bhh  = (const float*)d_in[8];
    const float* m_wih  = (const float*)d_in[9];
    const float* m_whh  = (const float*)d_in[10];
    const float* m_bih  = (const float*)d_in[11];
    const float* m_bhh  = (const float*)d_in[12];
    const float* norm_w = (const float*)d_in[13];
    const float* norm_b = (const float*)d_in[14];
    const float* macro_w= (const float*)d_in[15];
    const float* in_w   = (const float*)d_in[16];
    const float* in_b   = (const float*)d_in[17];
    const float* outp_w = (const float*)d_in[18];
    const float* outp_b = (const float*)d_in[19];
    const float* w1     = (const float*)d_in[20];
    const float* b1     = (const float*)d_in[21];
    const float* w2     = (const float*)d_in[22];
    const float* b2     = (const float*)d_in[23];
    const float* fw     = (const float*)d_in[24];
    const float* fb     = (const float*)d_in[25];
    float* out = (float*)d_out;

    // workspace layout (256B-aligned blocks)
    size_t off = 0;
    auto alloc = [&](size_t bytes) { char* q = (char*)d_ws + off; off += (bytes + 255) & ~(size_t)255; return q; };
    _Float16* W16h  = (_Float16*)alloc((size_t)2 * 8 * 128 * 384 * 2);
    _Float16* W16l  = (_Float16*)alloc((size_t)2 * 8 * 128 * 256 * 2);
    float*    biasP = (float*)alloc((size_t)2 * 8 * 128 * 4);
    _Float16* trW16 = (_Float16*)alloc((size_t)256 * 128 * 2);
    _Float16* hG    = (_Float16*)alloc((size_t)32 * 2 * 32 * 512 * 2);
    unsigned int* flags = (unsigned int*)alloc((size_t)32 * 256 * 8 * 4);   // 256 KB
    float*    ctx_s = (float*)alloc((size_t)B * H * 4);
    float*    ctx_m = (float*)alloc((size_t)B * H * 4);
    _Float16* xtr16 = (_Float16*)alloc((size_t)2 * B * S * 128 * 2);   // 64 MiB
    size_t off_before_hs = off;
    const size_t hs_elems = (size_t)2 * B * S * H;                     // both LSTMs
    const size_t need_full = off_before_hs + hs_elems * sizeof(float) + (1u << 20);
    const bool f32hs = ws_size >= need_full;

    prep_kernel<<<128, 256, 0, stream>>>(s_wih, s_whh, s_bih, s_bhh,
                                         m_wih, m_whh, m_bih, m_bhh,
                                         stw, mtw, W16h, W16l, biasP, trW16);
    xtr_kernel<<<B, 256, 0, stream>>>(x, trW16, stb, mtb, xtr16);
    (void)hipMemsetAsync(flags, 0, (size_t)32 * 256 * 8 * 4, stream);

    if (f32hs) {
        float* hs = (float*)alloc(hs_elems * sizeof(float));
        lstm_mfma<float><<<256, 256, 0, stream>>>(W16h, W16l, biasP, xtr16, hs, hG, flags);
        attn_ctx_kernel<float><<<dim3(B, 2), 256, 0, stream>>>(hs, hs + hs_elems / 2, ctx_s, ctx_m);
    } else {
        _Float16* hs = (_Float16*)alloc(hs_elems * sizeof(_Float16));
        lstm_mfma<_Float16><<<256, 256, 0, stream>>>(W16h, W16l, biasP, xtr16, hs, hG, flags);
        attn_ctx_kernel<_Float16><<<dim3(B, 2), 256, 0, stream>>>(hs, hs + hs_elems / 2, ctx_s, ctx_m);
    }

    tail_kernel<<<B, 256, 0, stream>>>(ctx_s, ctx_m,
                                       norm_w, norm_b, macro_w,
                                       in_w, in_b, outp_w, outp_b,
                                       w1, b1, w2, b2, fw, fb, out);
}

// Round 6
// 2316.684 us; speedup vs baseline: 5.5463x; 1.0030x over previous
//
#include <hip/hip_runtime.h>
#include <hip/hip_bf16.h>
#include <math.h>

#define B 512
#define S 256
#define D 128
#define H 256
#define G4 1024
#define NS 32
#define NH 8
#define DH 32

typedef _Float16 half8 __attribute__((ext_vector_type(8)));
typedef _Float16 half4v __attribute__((ext_vector_type(4)));
typedef float f32x4 __attribute__((ext_vector_type(4)));

__device__ __forceinline__ float sigm(float v) { return 1.f / (1.f + __expf(-v)); }
__device__ __forceinline__ float tanh_fast(float x) { float e = __expf(2.f * x); return 1.f - 2.f / (e + 1.f); }
__device__ __forceinline__ float cvtf(float v) { return v; }
__device__ __forceinline__ float cvtf(_Float16 v) { return (float)v; }

// ---------------- prep: fp16 weight slices in MFMA-friendly [n][k] layout ----------------
__global__ void prep_kernel(const float* __restrict__ s_wih, const float* __restrict__ s_whh,
                            const float* __restrict__ s_bih, const float* __restrict__ s_bhh,
                            const float* __restrict__ m_wih, const float* __restrict__ m_whh,
                            const float* __restrict__ m_bih, const float* __restrict__ m_bhh,
                            const float* __restrict__ stw, const float* __restrict__ mtw,
                            _Float16* __restrict__ W16h, _Float16* __restrict__ W16l,
                            float* __restrict__ biasP, _Float16* __restrict__ trW16)
{
    int tid = blockIdx.x * blockDim.x + threadIdx.x;
    int stride = gridDim.x * blockDim.x;
    for (int i = tid; i < 2 * 8 * 128 * 384; i += stride) {
        int k = i % 384; int n = (i / 384) % 128; int c = (i / (384 * 128)) % 8; int L = i / (384 * 128 * 8);
        int row = (n >> 5) * 256 + c * 32 + (n & 31);
        const float* wih = L ? m_wih : s_wih;
        const float* whh = L ? m_whh : s_whh;
        float v = (k < 128) ? wih[row * 128 + k] : whh[row * 256 + (k - 128)];
        W16h[i] = (_Float16)v;
    }
    for (int i = tid; i < 2 * 8 * 128 * 256; i += stride) {
        int k = i % 256; int n = (i / 256) % 128; int c = (i / (256 * 128)) % 8; int L = i / (256 * 128 * 8);
        int row = (n >> 5) * 256 + c * 32 + (n & 31);
        const float* whh = L ? m_whh : s_whh;
        float v = whh[row * 256 + k];
        _Float16 hi = (_Float16)v;
        W16l[i] = (_Float16)(v - (float)hi);
    }
    for (int i = tid; i < 2 * 8 * 128; i += stride) {
        int n = i % 128; int c = (i / 128) % 8; int L = i / (128 * 8);
        int row = (n >> 5) * 256 + c * 32 + (n & 31);
        biasP[i] = L ? (m_bih[row] + m_bhh[row]) : (s_bih[row] + s_bhh[row]);
    }
    for (int i = tid; i < 256 * 128; i += stride) {
        int k = i % 128, n = i / 128;
        trW16[i] = (_Float16)(n < 128 ? stw[n * 128 + k] : mtw[(n - 128) * 128 + k]);
    }
}

// ---------------- xtr: xtr16[L][b][t][d] = fp16(tanh(x @ trW^T + trb)), MFMA ----------------
__global__ __launch_bounds__(256, 1) void xtr_kernel(const float* __restrict__ x,
        const _Float16* __restrict__ trW16,
        const float* __restrict__ stb, const float* __restrict__ mtb,
        _Float16* __restrict__ xtr16)
{
    const int b = blockIdx.x;
    const int tid = threadIdx.x;
    const int w = tid >> 6, l = tid & 63, l15 = l & 15, l4 = l >> 4;

    __shared__ _Float16 xa[128 * 128];

    half8 bw[4][4];
#pragma unroll
    for (int kk = 0; kk < 4; kk++)
#pragma unroll
        for (int ni = 0; ni < 4; ni++)
            bw[kk][ni] = *(const half8*)(trW16 + (w * 64 + ni * 16 + l15) * 128 + kk * 32 + l4 * 8);
    float tb[4];
#pragma unroll
    for (int ni = 0; ni < 4; ni++) { int d = w * 64 + ni * 16 + l15; tb[ni] = d < 128 ? stb[d] : mtb[d - 128]; }

    for (int h2 = 0; h2 < 2; ++h2) {
        {
            int trow = tid >> 1, seg = tid & 1;
            const float* src = x + ((size_t)b * S + h2 * 128 + trow) * 128 + seg * 64;
            int swz = (trow & 7) << 4;
#pragma unroll
            for (int q8 = 0; q8 < 8; q8++) {
                float4 f0 = *(const float4*)(src + q8 * 8);
                float4 f1 = *(const float4*)(src + q8 * 8 + 4);
                half8 hv = { (_Float16)f0.x, (_Float16)f0.y, (_Float16)f0.z, (_Float16)f0.w,
                             (_Float16)f1.x, (_Float16)f1.y, (_Float16)f1.z, (_Float16)f1.w };
                int byte = ((seg * 64 + q8 * 8) * 2) ^ swz;
                *(half8*)((char*)(xa + trow * 128) + byte) = hv;
            }
        }
        __syncthreads();
        for (int mt = 0; mt < 8; ++mt) {
            int row = mt * 16 + l15;
            int swz = (row & 7) << 4;
            half8 af[4];
#pragma unroll
            for (int kk = 0; kk < 4; kk++) {
                int byte = ((kk * 32 + l4 * 8) * 2) ^ swz;
                af[kk] = *(const half8*)((const char*)(xa + row * 128) + byte);
            }
            f32x4 acc[4];
#pragma unroll
            for (int ni = 0; ni < 4; ni++) acc[ni] = (f32x4){ tb[ni], tb[ni], tb[ni], tb[ni] };
#pragma unroll
            for (int kk = 0; kk < 4; kk++)
#pragma unroll
                for (int ni = 0; ni < 4; ni++)
                    acc[ni] = __builtin_amdgcn_mfma_f32_16x16x32_f16(af[kk], bw[kk][ni], acc[ni], 0, 0, 0);
#pragma unroll
            for (int ni = 0; ni < 4; ni++) {
                int d = w * 64 + ni * 16 + l15;
                int Ls = d >> 7, dl = d & 127;
#pragma unroll
                for (int r = 0; r < 4; r++) {
                    int t = h2 * 128 + mt * 16 + l4 * 4 + r;
                    xtr16[(((size_t)Ls * B + b) * S + t) * 128 + dl] = (_Float16)tanh_fast(acc[ni][r]);
                }
            }
        }
        __syncthreads();
    }
}

// ---------------- persistent MFMA LSTM, L3-coherent flag sync (no L2 flush) ----------------
template<typename HT>
__global__ __launch_bounds__(256, 1) void lstm_mfma(
    const _Float16* __restrict__ W16h, const _Float16* __restrict__ W16l,
    const float* __restrict__ biasP,
    const _Float16* __restrict__ xtr16,
    HT* __restrict__ hs, _Float16* __restrict__ hG, unsigned int* __restrict__ flags)
{
    const int bid = blockIdx.x;
    const int sC = bid >> 5;
    const int g = bid & 31;
    const int L = g >> 4;
    const int bt = g & 15;
    const int b0 = bt * 32;
    const int tid = threadIdx.x;
    const int w = tid >> 6, l = tid & 63, l15 = l & 15, l4 = l >> 4;

    __shared__ _Float16 Ah[32 * 384];
    __shared__ _Float16 Al[32 * 256];
    __shared__ float gl[32][132];

    for (int i = tid; i < 32 * 384 * 2 / 16; i += 256) ((int4*)Ah)[i] = make_int4(0, 0, 0, 0);
    for (int i = tid; i < 32 * 256 * 2 / 16; i += 256) ((int4*)Al)[i] = make_int4(0, 0, 0, 0);

    const size_t wbh = ((size_t)(L * 8 + sC) * 128) * 384;
    const size_t wbl = ((size_t)(L * 8 + sC) * 128) * 256;
    half8 bwh[12][2], bwlo[8][2];
#pragma unroll
    for (int kk = 0; kk < 12; kk++)
#pragma unroll
        for (int ni = 0; ni < 2; ni++)
            bwh[kk][ni] = *(const half8*)(W16h + wbh + (size_t)(w * 32 + ni * 16 + l15) * 384 + kk * 32 + l4 * 8);
#pragma unroll
    for (int kk = 0; kk < 8; kk++)
#pragma unroll
        for (int ni = 0; ni < 2; ni++)
            bwlo[kk][ni] = *(const half8*)(W16l + wbl + (size_t)(w * 32 + ni * 16 + l15) * 256 + kk * 32 + l4 * 8);
    float bn[2];
#pragma unroll
    for (int ni = 0; ni < 2; ni++) bn[ni] = biasP[(L * 8 + sC) * 128 + w * 32 + ni * 16 + l15];

    const int b_pw = tid >> 3, jq = tid & 7;
    {
        const _Float16* src = xtr16 + (((size_t)L * B + b0 + b_pw) * S + 0) * 128 + jq * 16;
        half8 v0 = *(const half8*)src;
        half8 v1 = *(const half8*)(src + 8);
        int bswz = (b_pw & 7) << 4;
        *(half8*)((char*)(Ah + b_pw * 384) + ((jq * 32) ^ bswz)) = v0;
        *(half8*)((char*)(Ah + b_pw * 384) + ((jq * 32 + 16) ^ bswz)) = v1;
    }
    float cst[4] = { 0.f, 0.f, 0.f, 0.f };
    _Float16* hGg = hG + (size_t)g * 2 * 32 * 512;
    __syncthreads();

    for (int t = 0; t < S; ++t) {
        f32x4 acc[2][2];
#pragma unroll
        for (int mi = 0; mi < 2; mi++)
#pragma unroll
            for (int ni = 0; ni < 2; ni++) acc[mi][ni] = (f32x4){ bn[ni], bn[ni], bn[ni], bn[ni] };
#pragma unroll
        for (int kk = 0; kk < 12; kk++) {
            half8 ah[2], al[2];
#pragma unroll
            for (int mi = 0; mi < 2; mi++) {
                int row = mi * 16 + l15;
                int swz = (row & 7) << 4;
                if (kk < 4) {
                    int byte = ((kk * 32 + l4 * 8) * 2) ^ swz;
                    ah[mi] = *(const half8*)((const char*)(Ah + row * 384) + byte);
                } else {
                    int jb = ((kk - 4) * 32 + l4 * 8) * 2;
                    ah[mi] = *(const half8*)((const char*)(Ah + row * 384) + 256 + (jb ^ swz));
                    al[mi] = *(const half8*)((const char*)(Al + row * 256) + (jb ^ swz));
                }
            }
#pragma unroll
            for (int mi = 0; mi < 2; mi++)
#pragma unroll
                for (int ni = 0; ni < 2; ni++) {
                    acc[mi][ni] = __builtin_amdgcn_mfma_f32_16x16x32_f16(ah[mi], bwh[kk][ni], acc[mi][ni], 0, 0, 0);
                    if (kk >= 4) {
                        acc[mi][ni] = __builtin_amdgcn_mfma_f32_16x16x32_f16(ah[mi], bwlo[kk - 4][ni], acc[mi][ni], 0, 0, 0);
                        acc[mi][ni] = __builtin_amdgcn_mfma_f32_16x16x32_f16(al[mi], bwh[kk][ni], acc[mi][ni], 0, 0, 0);
                    }
                }
        }
        half8 xp0 = {}, xp1 = {};
        if (t < S - 1) {
            const _Float16* src = xtr16 + (((size_t)L * B + b0 + b_pw) * S + (t + 1)) * 128 + jq * 16;
            xp0 = *(const half8*)src;
            xp1 = *(const half8*)(src + 8);
        }
#pragma unroll
        for (int mi = 0; mi < 2; mi++)
#pragma unroll
            for (int ni = 0; ni < 2; ni++)
#pragma unroll
                for (int r = 0; r < 4; r++)
                    gl[mi * 16 + l4 * 4 + r][w * 32 + ni * 16 + l15] = acc[mi][ni][r];
        __syncthreads();   // B1: gates visible
        {
            f32x4 iv = *(const f32x4*)&gl[b_pw][0 + jq * 4];
            f32x4 fv = *(const f32x4*)&gl[b_pw][32 + jq * 4];
            f32x4 gv = *(const f32x4*)&gl[b_pw][64 + jq * 4];
            f32x4 ov = *(const f32x4*)&gl[b_pw][96 + jq * 4];
            float hv[4];
            _Float16 hh[4], hl[4];
#pragma unroll
            for (int q = 0; q < 4; q++) {
                float cc = sigm(fv[q]) * cst[q] + sigm(iv[q]) * tanh_fast(gv[q]);
                cst[q] = cc;
                hv[q] = sigm(ov[q]) * tanh_fast(cc);
                hh[q] = (_Float16)hv[q];
                hl[q] = (_Float16)(hv[q] - (float)hh[q]);
            }
            size_t hidx = (((size_t)L * B + b0 + b_pw) * S + t) * H + sC * 32 + jq * 4;
            if constexpr (sizeof(HT) == 4) {
                *(float4*)((float*)hs + hidx) = make_float4(hv[0], hv[1], hv[2], hv[3]);
            } else {
                half4v h4 = { hh[0], hh[1], hh[2], hh[3] };
                *(half4v*)((_Float16*)hs + hidx) = h4;
            }
            if (t < S - 1) {
                int par = t & 1;
                _Float16* dsth = hGg + par * 32 * 512 + b_pw * 512 + sC * 32 + jq * 4;
                half4v dhi = { hh[0], hh[1], hh[2], hh[3] };
                half4v dlo = { hl[0], hl[1], hl[2], hl[3] };
                // device-coherent (L3) stores: bypass non-coherent per-XCD L2
                asm volatile("global_store_dwordx2 %0, %1, off sc0 sc1" :: "v"(dsth), "v"(dhi) : "memory");
                asm volatile("global_store_dwordx2 %0, %1, off sc0 sc1" :: "v"(dsth + 256), "v"(dlo) : "memory");
                int bswz = (b_pw & 7) << 4;
                *(half8*)((char*)(Ah + b_pw * 384) + ((jq * 32) ^ bswz)) = xp0;
                *(half8*)((char*)(Ah + b_pw * 384) + ((jq * 32 + 16) ^ bswz)) = xp1;
            }
        }
        if (t < S - 1) {
            // drain own dc-stores (inline-asm ops are invisible to compiler waitcnt tracking)
            asm volatile("s_waitcnt vmcnt(0)" ::: "memory");
            __syncthreads();   // B2: all threads' h-chunk stores are at L3
            if (tid == 0) {
                unsigned int one = 1u;
                const unsigned int* fp = flags + (((unsigned)g * 256u + (unsigned)t) * 8u + (unsigned)sC);
                asm volatile("global_store_dword %0, %1, off sc0 sc1" :: "v"(fp), "v"(one) : "memory");
            }
            // each thread depends only on writer sC == jq: poll that flag directly
            {
                const unsigned int* fp = flags + (((unsigned)g * 256u + (unsigned)t) * 8u + (unsigned)jq);
                unsigned int v;
                while (true) {
                    asm volatile("global_load_dword %0, %1, off sc0 sc1\n\ts_waitcnt vmcnt(0)"
                                 : "=v"(v) : "v"(fp) : "memory");
                    if (v) break;
                    __builtin_amdgcn_s_sleep(2);
                }
            }
            {
                int par = t & 1;
                const _Float16* srch = hGg + par * 32 * 512 + b_pw * 512 + jq * 32;
                half8 vh[4], vl[4];
#pragma unroll
                for (int u = 0; u < 4; u++) {
                    asm volatile("global_load_dwordx4 %0, %1, off sc0 sc1" : "=v"(vh[u]) : "v"(srch + u * 8) : "memory");
                    asm volatile("global_load_dwordx4 %0, %1, off sc0 sc1" : "=v"(vl[u]) : "v"(srch + 256 + u * 8) : "memory");
                }
                asm volatile("s_waitcnt vmcnt(0)" ::: "memory");
                __builtin_amdgcn_sched_barrier(0);
                int bswz = (b_pw & 7) << 4;
#pragma unroll
                for (int u = 0; u < 4; u++) {
                    int jb = (jq * 32 + u * 8) * 2;
                    *(half8*)((char*)(Ah + b_pw * 384) + 256 + (jb ^ bswz)) = vh[u];
                    *(half8*)((char*)(Al + b_pw * 256) + (jb ^ bswz)) = vl[u];
                }
            }
            __syncthreads();   // B4: h ready for next step
        }
    }
}

// ---------------- attention context ----------------
template<typename HT>
__global__ __launch_bounds__(256) void attn_ctx_kernel(const HT* __restrict__ hs_s, const HT* __restrict__ hs_m,
                                                       float* __restrict__ ctx_s, float* __restrict__ ctx_m)
{
    const int b = blockIdx.x;
    const int L = blockIdx.y;
    const HT* hsb = (L ? hs_m : hs_s) + (size_t)b * S * H;
    float* ctx = (L ? ctx_m : ctx_s) + b * H;
    const int tid = threadIdx.x;

    __shared__ float hlast[H];
    __shared__ float dist[S];
    __shared__ float red[4];

    hlast[tid] = cvtf(hsb[(size_t)(S - 1) * H + tid]);
    __syncthreads();

    float s = 0.f;
    {
        const HT* row = hsb + (size_t)tid * H;
        if constexpr (sizeof(HT) == 2) {
            const half8* r8 = (const half8*)row;
#pragma unroll 4
            for (int c = 0; c < H / 8; ++c) {
                half8 v = r8[c];
#pragma unroll
                for (int j = 0; j < 8; j++) s = fmaf((float)v[j], hlast[c * 8 + j], s);
            }
        } else {
            const float4* r4 = (const float4*)row;
#pragma unroll 4
            for (int c = 0; c < H / 4; ++c) {
                float4 v = r4[c];
                s = fmaf(v.x, hlast[c * 4 + 0], s);
                s = fmaf(v.y, hlast[c * 4 + 1], s);
                s = fmaf(v.z, hlast[c * 4 + 2], s);
                s = fmaf(v.w, hlast[c * 4 + 3], s);
            }
        }
    }
    float v = s;
    for (int o = 32; o > 0; o >>= 1) v += __shfl_down(v, o);
    if ((tid & 63) == 0) red[tid >> 6] = v;
    __syncthreads();
    float denom = red[0] + red[1] + red[2] + red[3];
    dist[tid] = s / denom;
    __syncthreads();

    float acc = 0.f;
    for (int t = 0; t < S; ++t) acc = fmaf(dist[t], cvtf(hsb[(size_t)t * H + tid]), acc);
    ctx[tid] = acc;
}

// ---------------- tail ----------------
__global__ __launch_bounds__(256) void tail_kernel(
    const float* __restrict__ ctx_s, const float* __restrict__ ctx_m,
    const float* __restrict__ norm_w, const float* __restrict__ norm_b,
    const float* __restrict__ macro_w,
    const float* __restrict__ in_w, const float* __restrict__ in_b,
    const float* __restrict__ outp_w, const float* __restrict__ outp_b,
    const float* __restrict__ w1, const float* __restrict__ b1,
    const float* __restrict__ w2, const float* __restrict__ b2,
    const float* __restrict__ fw, const float* __restrict__ fb,
    float* __restrict__ out)
{
    const int b = blockIdx.x;
    const int tid = threadIdx.x;

    __shared__ float ml[NS][H];
    __shared__ float buf[NS][H];
    __shared__ float qh[NS][DH], kh[NS][DH], vh[NS][DH], sc[NS][NS];
    __shared__ float red[4];

    float cs = ctx_s[b * H + tid];
    float v = cs;
    for (int o = 32; o > 0; o >>= 1) v += __shfl_down(v, o);
    if ((tid & 63) == 0) red[tid >> 6] = v;
    __syncthreads();
    float mean = (red[0] + red[1] + red[2] + red[3]) * (1.f / H);
    float dv = cs - mean;
    __syncthreads();
    v = dv * dv;
    for (int o = 32; o > 0; o >>= 1) v += __shfl_down(v, o);
    if ((tid & 63) == 0) red[tid >> 6] = v;
    __syncthreads();
    float stdv = sqrtf((red[0] + red[1] + red[2] + red[3]) * (1.f / (H - 1))) + 1e-8f;
    float z = dv / stdv;
    float cm = ctx_m[b * H + tid];
    float mwv = macro_w[0];
    for (int n = 0; n < NS; ++n)
        ml[n][tid] = norm_w[n * H + tid] * z + norm_b[n * H + tid] + mwv * cm;
    __syncthreads();

    const int dloc = tid & 31;
    const int iset = tid >> 5;
    const float scale = 0.17677669529663687f;
    for (int h = 0; h < NH; ++h) {
        {
            int rq = h * DH + dloc;
            int rk = H + h * DH + dloc;
            int rv = 2 * H + h * DH + dloc;
            float aq[4], ak[4], av[4];
#pragma unroll
            for (int r = 0; r < 4; r++) { aq[r] = in_b[rq]; ak[r] = in_b[rk]; av[r] = in_b[rv]; }
            for (int k = 0; k < H; ++k) {
                float wq = in_w[rq * H + k];
                float wk = in_w[rk * H + k];
                float wv = in_w[rv * H + k];
#pragma unroll
                for (int r = 0; r < 4; r++) {
                    float m = ml[iset + 8 * r][k];
                    aq[r] = fmaf(m, wq, aq[r]); ak[r] = fmaf(m, wk, ak[r]); av[r] = fmaf(m, wv, av[r]);
                }
            }
#pragma unroll
            for (int r = 0; r < 4; r++) { qh[iset + 8 * r][dloc] = aq[r]; kh[iset + 8 * r][dloc] = ak[r]; vh[iset + 8 * r][dloc] = av[r]; }
        }
        __syncthreads();
        {
            int i = tid >> 3;
            int j0 = (tid & 7) * 4;
            float a[4] = { 0.f, 0.f, 0.f, 0.f };
            for (int d = 0; d < DH; ++d) {
                float q = qh[i][d];
#pragma unroll
                for (int jj = 0; jj < 4; jj++) a[jj] = fmaf(q, kh[j0 + jj][d], a[jj]);
            }
#pragma unroll
            for (int jj = 0; jj < 4; jj++) sc[i][j0 + jj] = a[jj] * scale;
        }
        __syncthreads();
        if (tid < NS) {
            float mx = -1e30f;
            for (int j = 0; j < NS; j++) mx = fmaxf(mx, sc[tid][j]);
            float sm = 0.f, e[NS];
            for (int j = 0; j < NS; j++) { e[j] = __expf(sc[tid][j] - mx); sm += e[j]; }
            float inv = 1.f / sm;
            for (int j = 0; j < NS; j++) sc[tid][j] = e[j] * inv;
        }
        __syncthreads();
        {
            int i = tid >> 3;
            int d0 = (tid & 7) * 4;
            float a[4] = { 0.f, 0.f, 0.f, 0.f };
            for (int j = 0; j < NS; ++j) {
                float sv = sc[i][j];
#pragma unroll
                for (int dd = 0; dd < 4; dd++) a[dd] = fmaf(sv, vh[j][d0 + dd], a[dd]);
            }
#pragma unroll
            for (int dd = 0; dd < 4; dd++) buf[i][h * DH + d0 + dd] = a[dd];
        }
        __syncthreads();
    }

    {
        float acc32[NS];
        float ob = outp_b[tid];
#pragma unroll
        for (int t = 0; t < NS; t++) acc32[t] = ob;
        for (int k = 0; k < H; ++k) {
            float w = outp_w[tid * H + k];
#pragma unroll
            for (int t = 0; t < NS; t++) acc32[t] = fmaf(buf[t][k], w, acc32[t]);
        }
#pragma unroll
        for (int t = 0; t < NS; t++) ml[t][tid] += acc32[t];
    }
    __syncthreads();

    float acc_o[NS];
    {
        float b2v = b2[tid];
#pragma unroll
        for (int t = 0; t < NS; t++) acc_o[t] = b2v;
    }
    for (int jc = 0; jc < 4; ++jc) {
        float hid[NS];
        {
            float b1v = b1[jc * H + tid];
#pragma unroll
            for (int t = 0; t < NS; t++) hid[t] = b1v;
            for (int k = 0; k < H; ++k) {
                float w = w1[(size_t)(jc * H + tid) * H + k];
#pragma unroll
                for (int t = 0; t < NS; t++) hid[t] = fmaf(ml[t][k], w, hid[t]);
            }
        }
        __syncthreads();
#pragma unroll
        for (int t = 0; t < NS; t++) buf[t][tid] = fmaxf(hid[t], 0.f);
        __syncthreads();
        for (int k = 0; k < H; ++k) {
            float w = w2[(size_t)tid * G4 + jc * H + k];
#pragma unroll
            for (int t = 0; t < NS; t++) acc_o[t] = fmaf(buf[t][k], w, acc_o[t]);
        }
        __syncthreads();
    }

    float p = 0.f;
#pragma unroll
    for (int t = 0; t < NS; t++) p += tanhf(ml[t][tid] + acc_o[t]);
    p *= (1.f / NS);
    v = p * fw[tid];
    for (int o = 32; o > 0; o >>= 1) v += __shfl_down(v, o);
    if ((tid & 63) == 0) red[tid >> 6] = v;
    __syncthreads();
    if (tid == 0) out[b] = red[0] + red[1] + red[2] + red[3] + fb[0];
}

// ---------------- host ----------------
extern "C" void kernel_launch(void* const* d_in, const int* in_sizes, int n_in,
                              void* d_out, int out_size, void* d_ws, size_t ws_size,
                              hipStream_t stream) {
    const float* x      = (const float*)d_in[0];
    const float* stw    = (const float*)d_in[1];
    const float* stb    = (const float*)d_in[2];
    const float* mtw    = (const float*)d_in[3];
    const float* mtb    = (const float*)d_in[4];
    const float* s_wih  = (const float*)d_in[5];
    const float* s_whh  = (const float*)d_in[6];
    const float* s_bih  = (const float*)d_in[7];
    const float* s_bhh  = (const float*)d_in[8];
    const float* m_wih  = (const float*)d_in[9];
    const float* m_whh  = (const float*)d_in[10];
    const float* m_bih  = (const float*)d_in[11];
    const float* m_bhh  = (const float*)d_in[12];
    const float* norm_w = (const float*)d_in[13];
    const float* norm_b = (const float*)d_in[14];
    const float* macro_w= (const float*)d_in[15];
    const float* in_w   = (const float*)d_in[16];
    const float* in_b   = (const float*)d_in[17];
    const float* outp_w = (const float*)d_in[18];
    const float* outp_b = (const float*)d_in[19];
    const float* w1     = (const float*)d_in[20];
    const float* b1     = (const float*)d_in[21];
    const float* w2     = (const float*)d_in[22];
    const float* b2     = (const float*)d_in[23];
    const float* fw     = (const float*)d_in[24];
    const float* fb     = (const float*)d_in[25];
    float* out = (float*)d_out;

    // workspace layout (256B-aligned blocks)
    size_t off = 0;
    auto alloc = [&](size_t bytes) { char* q = (char*)d_ws + off; off += (bytes + 255) & ~(size_t)255; return q; };
    _Float16* W16h  = (_Float16*)alloc((size_t)2 * 8 * 128 * 384 * 2);
    _Float16* W16l  = (_Float16*)alloc((size_t)2 * 8 * 128 * 256 * 2);
    float*    biasP = (float*)alloc((size_t)2 * 8 * 128 * 4);
    _Float16* trW16 = (_Float16*)alloc((size_t)256 * 128 * 2);
    _Float16* hG    = (_Float16*)alloc((size_t)32 * 2 * 32 * 512 * 2);
    unsigned int* flags = (unsigned int*)alloc((size_t)32 * 256 * 8 * 4);   // 256 KB
    float*    ctx_s = (float*)alloc((size_t)B * H * 4);
    float*    ctx_m = (float*)alloc((size_t)B * H * 4);
    _Float16* xtr16 = (_Float16*)alloc((size_t)2 * B * S * 128 * 2);   // 64 MiB
    size_t off_before_hs = off;
    const size_t hs_elems = (size_t)2 * B * S * H;                     // both LSTMs
    const size_t need_full = off_before_hs + hs_elems * sizeof(float) + (1u << 20);
    const bool f32hs = ws_size >= need_full;

    prep_kernel<<<128, 256, 0, stream>>>(s_wih, s_whh, s_bih, s_bhh,
                                         m_wih, m_whh, m_bih, m_bhh,
                                         stw, mtw, W16h, W16l, biasP, trW16);
    xtr_kernel<<<B, 256, 0, stream>>>(x, trW16, stb, mtb, xtr16);
    (void)hipMemsetAsync(flags, 0, (size_t)32 * 256 * 8 * 4, stream);

    if (f32hs) {
        float* hs = (float*)alloc(hs_elems * sizeof(float));
        lstm_mfma<float><<<256, 256, 0, stream>>>(W16h, W16l, biasP, xtr16, hs, hG, flags);
        attn_ctx_kernel<float><<<dim3(B, 2), 256, 0, stream>>>(hs, hs + hs_elems / 2, ctx_s, ctx_m);
    } else {
        _Float16* hs = (_Float16*)alloc(hs_elems * sizeof(_Float16));
        lstm_mfma<_Float16><<<256, 256, 0, stream>>>(W16h, W16l, biasP, xtr16, hs, hG, flags);
        attn_ctx_kernel<_Float16><<<dim3(B, 2), 256, 0, stream>>>(hs, hs + hs_elems / 2, ctx_s, ctx_m);
    }

    tail_kernel<<<B, 256, 0, stream>>>(ctx_s, ctx_m,
                                       norm_w, norm_b, macro_w,
                                       in_w, in_b, outp_w, outp_b,
                                       w1, b1, w2, b2, fw, fb, out);
}